// Round 4
// baseline (202.231 us; speedup 1.0000x reference)
//
#include <hip/hip_runtime.h>
#include <stdint.h>

#define B_ 2
#define T_ 2048
#define C_ 1024
#define H_ 16
#define DH_ 64
#define M_ (B_*T_)   // 4096

typedef short bhalf8 __attribute__((ext_vector_type(8)));
typedef float floatx4 __attribute__((ext_vector_type(4)));

__device__ __forceinline__ short f2bf(float f) {
  unsigned u = __float_as_uint(f);
  u += 0x7fffu + ((u >> 16) & 1u);   // round-to-nearest-even
  return (short)(u >> 16);
}
__device__ __forceinline__ float bf2f(short s) {
  return __uint_as_float(((unsigned)(unsigned short)s) << 16);
}

// async global->LDS, 16B per lane; lds_dst wave-uniform (lane -> +lane*16)
__device__ __forceinline__ void gll16(void* lds_dst, const void* g_src) {
  __builtin_amdgcn_global_load_lds(
      reinterpret_cast<const uint32_t __attribute__((address_space(1)))*>(
          reinterpret_cast<uintptr_t>(g_src)),
      reinterpret_cast<uint32_t __attribute__((address_space(3)))*>(
          reinterpret_cast<uintptr_t>(lds_dst)),
      16, 0, 0);
}

__global__ void cvt_all(
    const float* __restrict__ x,  const float* __restrict__ wq,
    const float* __restrict__ wk, const float* __restrict__ wv,
    const float* __restrict__ wo,
    short* __restrict__ xb, short* __restrict__ wqb, short* __restrict__ wkb,
    short* __restrict__ wvb, short* __restrict__ wob)
{
  int i = blockIdx.x * blockDim.x + threadIdx.x;
  const float* s; short* d; int off;
  if (i < (M_*C_/4)) { s = x; d = xb; off = i; }
  else {
    int j = i - M_*C_/4;
    int w = j >> 18;                     // C_*C_/4 == 1<<18
    off = j & ((1<<18) - 1);
    s = (w==0) ? wq : (w==1) ? wk : (w==2) ? wv : wo;
    d = (w==0) ? wqb : (w==1) ? wkb : (w==2) ? wvb : wob;
  }
  float4 v = ((const float4*)s)[off];
  short4 o;
  o.x = f2bf(v.x); o.y = f2bf(v.y); o.z = f2bf(v.z); o.w = f2bf(v.w);
  ((short4*)d)[off] = o;
}

// R13: fused Q/K/V projection, BM=256 x BN=192 tile (grid 256 = 16 N x 16 M,
// full CU coverage; was 192 blocks = 64 CUs idle). B = contiguous [Wq;Wk;Wv]
// (3072 rows). 8 waves (2M x 4N, wave = 128 tok x 48 ch), BK=64, 112 KiB LDS,
// same 4-phase counted-vmcnt pipeline (12 MFMA/phase). No V operand swap.
// Epilogue via LDS: deposit raw C into token-major Ct[256][200] (col-XOR
// swizzle by (tok&3)<<3), then:
//   pass A (token-major): RoPE'd Q/K -> Qb/Kb, coalesced 16B stores
//   pass B (channel-major): K^T (self-RoPE) -> Kt, V^T -> Vt
// RoPE pairs (dh, dh^32) span waves at BN=192 -> must go through LDS.
__global__ __launch_bounds__(512, 2) void gemm_qkv(
    const short* __restrict__ X, const short* __restrict__ Wcat,
    short* __restrict__ Qb, short* __restrict__ Kb, short* __restrict__ Vt,
    short* __restrict__ Kt)
{
  __shared__ __align__(16) short SM[57344];   // 112 KiB
  // As: [2][256*64] at 0 / 16384 ; Bs: [2][192*64] at 32768 / 45056
  short* ASb0 = SM;          short* ASb1 = SM + 16384;
  short* BSb0 = SM + 32768;  short* BSb1 = SM + 45056;
  short* Ct   = SM;                            // epilogue: [256 tok][200]

  const int tid  = threadIdx.x;
  const int lane = tid & 63;
  const int wid  = tid >> 6;
  const int l15  = lane & 15;
  const int quad = lane >> 4;
  const int wr   = wid >> 2;          // 0..1 (M half, 128 tokens)
  const int wc   = wid & 3;           // 0..3 (N quarter, 48 channels)
  const int wcb  = wc * 48;

  const int bid = blockIdx.x;
  const int wg  = (bid & 7) * 32 + (bid >> 3);   // XCD swizzle, 256%8==0
  const int nx  = wg & 15;
  const int m0  = (wg >> 4) << 8;
  const int n0g = nx * 192;                      // global concat channel base

  const short* Ab = X    + (size_t)m0 * C_;
  const short* Bb = Wcat + (size_t)n0g * C_;

  const int r_loc = tid >> 3;        // 0..63: row within a 64-row unit
  const int g_lin = tid & 7;

  auto stA = [&](short* base, int q, int k0) {   // A unit q (64 rows)
    int row = (q << 6) + r_loc;
    int gs  = g_lin ^ (row & 7);
    gll16(base + (q << 12) + (wid << 9), Ab + (size_t)row * C_ + k0 + (gs << 3));
  };
  auto stB = [&](short* base, int q, int k0) {   // B unit q (64 rows, q<3)
    int row = (q << 6) + r_loc;
    int gs  = g_lin ^ (row & 7);
    gll16(base + (q << 12) + (wid << 9), Bb + (size_t)row * C_ + k0 + (gs << 3));
  };

  floatx4 acc[8][3] = {};

  // prologue: issue order = read priority (p1 needs B0,B1,B2,A0,A2; p2 A1,A3)
  stB(BSb0, 0, 0); stB(BSb0, 1, 0); stB(BSb0, 2, 0);
  stA(ASb0, 0, 0); stA(ASb0, 2, 0);
  stA(ASb0, 1, 0); stA(ASb0, 3, 0);
  asm volatile("s_waitcnt vmcnt(2)" ::: "memory");   // first 5 landed
  __builtin_amdgcn_s_barrier();
  __builtin_amdgcn_sched_barrier(0);

  for (int t = 0; t < 16; ++t) {
    short* Ac = (t & 1) ? ASb1 : ASb0;
    short* Bc = (t & 1) ? BSb1 : BSb0;
    short* An = (t & 1) ? ASb0 : ASb1;
    short* Bn = (t & 1) ? BSb0 : BSb1;
    const int kn = (t + 1) << 6;
    const bool pf = (t < 15);
    bhalf8 aF[4], bF[3];

    // ---- phase 1: ks=0, m-frags 0..3 + B ks=0 ; stage B0,B1 ----
#pragma unroll
    for (int i = 0; i < 4; ++i) {
      int row = (wr << 7) + (i << 4) + l15;
      aF[i] = *(const bhalf8*)&Ac[(row << 6) + ((quad ^ (row & 7)) << 3)];
    }
#pragma unroll
    for (int n = 0; n < 3; ++n) {
      int row = wcb + (n << 4) + l15;
      bF[n] = *(const bhalf8*)&Bc[(row << 6) + ((quad ^ (row & 7)) << 3)];
    }
    if (pf) { stB(Bn, 0, kn); stB(Bn, 1, kn); }
    __builtin_amdgcn_s_barrier();
    asm volatile("s_waitcnt lgkmcnt(0)" ::: "memory");
    __builtin_amdgcn_sched_barrier(0);
    __builtin_amdgcn_s_setprio(1);
#pragma unroll
    for (int i = 0; i < 4; ++i)
#pragma unroll
      for (int n = 0; n < 3; ++n)
        acc[i][n] = __builtin_amdgcn_mfma_f32_16x16x32_bf16(aF[i], bF[n], acc[i][n], 0, 0, 0);
    __builtin_amdgcn_s_setprio(0);
    if (pf) { asm volatile("s_waitcnt vmcnt(2)" ::: "memory"); }  // A1,A3 landed
    else    { asm volatile("s_waitcnt vmcnt(0)" ::: "memory"); }  // last tile: drain
    __builtin_amdgcn_s_barrier();
    __builtin_amdgcn_sched_barrier(0);

    // ---- phase 2: ks=0, m-frags 4..7 ; stage B2,A0 ----
#pragma unroll
    for (int i = 0; i < 4; ++i) {
      int row = (wr << 7) + ((4 + i) << 4) + l15;
      aF[i] = *(const bhalf8*)&Ac[(row << 6) + ((quad ^ (row & 7)) << 3)];
    }
    if (pf) { stB(Bn, 2, kn); stA(An, 0, kn); }
    __builtin_amdgcn_s_barrier();
    asm volatile("s_waitcnt lgkmcnt(0)" ::: "memory");
    __builtin_amdgcn_sched_barrier(0);
    __builtin_amdgcn_s_setprio(1);
#pragma unroll
    for (int i = 0; i < 4; ++i)
#pragma unroll
      for (int n = 0; n < 3; ++n)
        acc[4 + i][n] = __builtin_amdgcn_mfma_f32_16x16x32_bf16(aF[i], bF[n], acc[4 + i][n], 0, 0, 0);
    __builtin_amdgcn_s_setprio(0);
    asm volatile("s_waitcnt vmcnt(4)" ::: "memory");
    __builtin_amdgcn_s_barrier();
    __builtin_amdgcn_sched_barrier(0);

    // ---- phase 3: ks=1, m-frags 0..3 + B ks=1 ; stage A2 ----
#pragma unroll
    for (int i = 0; i < 4; ++i) {
      int row = (wr << 7) + (i << 4) + l15;
      aF[i] = *(const bhalf8*)&Ac[(row << 6) + (((4 + quad) ^ (row & 7)) << 3)];
    }
#pragma unroll
    for (int n = 0; n < 3; ++n) {
      int row = wcb + (n << 4) + l15;
      bF[n] = *(const bhalf8*)&Bc[(row << 6) + (((4 + quad) ^ (row & 7)) << 3)];
    }
    if (pf) { stA(An, 2, kn); }
    __builtin_amdgcn_s_barrier();
    asm volatile("s_waitcnt lgkmcnt(0)" ::: "memory");
    __builtin_amdgcn_sched_barrier(0);
    __builtin_amdgcn_s_setprio(1);
#pragma unroll
    for (int i = 0; i < 4; ++i)
#pragma unroll
      for (int n = 0; n < 3; ++n)
        acc[i][n] = __builtin_amdgcn_mfma_f32_16x16x32_bf16(aF[i], bF[n], acc[i][n], 0, 0, 0);
    __builtin_amdgcn_s_setprio(0);
    asm volatile("s_waitcnt vmcnt(5)" ::: "memory");
    __builtin_amdgcn_s_barrier();
    __builtin_amdgcn_sched_barrier(0);

    // ---- phase 4: ks=1, m-frags 4..7 ; stage A1,A3 ----
#pragma unroll
    for (int i = 0; i < 4; ++i) {
      int row = (wr << 7) + ((4 + i) << 4) + l15;
      aF[i] = *(const bhalf8*)&Ac[(row << 6) + (((4 + quad) ^ (row & 7)) << 3)];
    }
    if (pf) { stA(An, 1, kn); stA(An, 3, kn); }
    __builtin_amdgcn_s_barrier();
    asm volatile("s_waitcnt lgkmcnt(0)" ::: "memory");
    __builtin_amdgcn_sched_barrier(0);
    __builtin_amdgcn_s_setprio(1);
#pragma unroll
    for (int i = 0; i < 4; ++i)
#pragma unroll
      for (int n = 0; n < 3; ++n)
        acc[4 + i][n] = __builtin_amdgcn_mfma_f32_16x16x32_bf16(aF[i], bF[n], acc[4 + i][n], 0, 0, 0);
    __builtin_amdgcn_s_setprio(0);
    asm volatile("s_waitcnt vmcnt(2)" ::: "memory");   // B*,A0,A2 of next tile
    __builtin_amdgcn_s_barrier();
    __builtin_amdgcn_sched_barrier(0);
  }
  // As/Bs dead -> Ct reusable

  // ---- deposit raw C: Ct[tok][ch], rows padded to 200, col-XOR (tok&3)<<3 ----
#pragma unroll
  for (int m = 0; m < 8; ++m)
#pragma unroll
    for (int n = 0; n < 3; ++n)
#pragma unroll
      for (int r = 0; r < 4; ++r) {
        int tok = (wr << 7) + (m << 4) + (quad << 2) + r;
        int ch  = wcb + (n << 4) + l15;
        Ct[tok * 200 + (ch ^ ((tok & 3) << 3))] = f2bf(acc[m][n][r]);
      }
  __syncthreads();

  const int bb = m0 >> 11, tbase = m0 & (T_ - 1);
  const float LAM = -0.4152410118609203f;      // -log2(10000)/32

  // ---- pass A: token-major RoPE'd Q/K stores (channels o < 2048) ----
  int qkch = 2048 - n0g; qkch = qkch < 0 ? 0 : (qkch > 192 ? 192 : qkch);
  const int ncg = qkch >> 3;                   // chunks of 8 ch: 0, 16, or 24
  if (ncg > 0) {
    float fj[8];
#pragma unroll
    for (int j = 0; j < 8; ++j) fj[j] = exp2f(LAM * (float)j);
    const int iters = ncg >> 1;                // 256*ncg/512
    for (int it2 = 0; it2 < iters; ++it2) {
      int lin = it2 * 512 + tid;
      int tok, cg;
      if (ncg == 24) { tok = (lin * 2731) >> 16; cg = lin - tok * 24; }
      else           { tok = lin >> 4;           cg = lin & 15; }
      int o0 = n0g + cg * 8;
      int dh0 = o0 & 63, hh = (o0 & 1023) >> 6, kind = o0 >> 10;
      int xk = (tok & 3) << 3;
      bhalf8 va = *(const bhalf8*)&Ct[tok * 200 + ((cg * 8) ^ xk)];
      bhalf8 vb = *(const bhalf8*)&Ct[tok * 200 + (((cg * 8) ^ 32) ^ xk)];
      float fb = exp2f(LAM * (float)(dh0 & 31));
      float tt = (float)(tbase + tok);
      float sgn = (dh0 < 32) ? -1.f : 1.f;
      bhalf8 y;
#pragma unroll
      for (int j = 0; j < 8; ++j) {
        float ang = tt * (fb * fj[j]);
        float sn = __sinf(ang), cs = __cosf(ang);
        y[j] = f2bf(bf2f(va[j]) * cs + sgn * bf2f(vb[j]) * sn);
      }
      short* Cb = kind ? Kb : Qb;
      *(bhalf8*)&Cb[(((size_t)(bb * H_ + hh)) * T_ + (tbase + tok)) * DH_ + dh0] = y;
    }
  }

  // ---- pass B: channel-major; K^T (self-RoPE) -> Kt, V^T -> Vt ----
  int lo = 1024 - n0g; lo = lo < 0 ? 0 : (lo > 192 ? 192 : lo);
  const int cnt = 192 - lo;                    // channels with o >= 1024
  if (cnt > 0) {
    const int iters = cnt >> 4;                // cnt*32/512
    for (int it2 = 0; it2 < iters; ++it2) {
      int lin = it2 * 512 + tid;
      int ch = lo + (lin >> 5), tg = lin & 31;
      int o = n0g + ch;
      bhalf8 y;
      if (o < 2048) {                          // K: transpose + RoPE
        int dh = o & 63, hh = (o & 1023) >> 6;
        float fb = exp2f(LAM * (float)(dh & 31));
        float sgn = (dh < 32) ? -1.f : 1.f;
        int chp = ch ^ 32;
#pragma unroll
        for (int j = 0; j < 8; ++j) {
          int tok = tg * 8 + j; int xk = (tok & 3) << 3;
          float v  = bf2f(Ct[tok * 200 + (ch  ^ xk)]);
          float vp = bf2f(Ct[tok * 200 + (chp ^ xk)]);
          float ang = (float)(tbase + tok) * fb;
          float sn = __sinf(ang), cs = __cosf(ang);
          y[j] = f2bf(v * cs + sgn * vp * sn);
        }
        *(bhalf8*)&Kt[(((size_t)(bb * H_ + hh)) * DH_ + dh) * T_ + tbase + tg * 8] = y;
      } else {                                 // V: transpose only
#pragma unroll
        for (int j = 0; j < 8; ++j) {
          int tok = tg * 8 + j; int xk = (tok & 3) << 3;
          y[j] = Ct[tok * 200 + (ch ^ xk)];
        }
        *(bhalf8*)&Vt[(size_t)bb * (C_ * T_) + (size_t)(o - 2048) * T_ + tbase + tg * 8] = y;
      }
    }
  }
}

// Final projection. 3-buffer 2-tile-lookahead counted-vmcnt pipeline.
__global__ __launch_bounds__(256) void gemm_out(
    const short* __restrict__ A, const short* __restrict__ Bm, float* __restrict__ Cf)
{
  __shared__ __align__(16) short As[3][128*64];   // 16 KB per buf
  __shared__ __align__(16) short Bs[3][64*64];    // 8 KB per buf
  const int tid = threadIdx.x, lane = tid & 63, wv = tid >> 6;
  const int l15 = lane & 15, quad = lane >> 4;
  const int n0 = blockIdx.x << 6;
  const int m0 = blockIdx.y << 7;

  const short* Ab = A  + (size_t)m0 * C_;
  const short* Bb = Bm + (size_t)n0 * C_;

  auto stage = [&](int buf, int k0) {
#pragma unroll
    for (int i = 0; i < 4; ++i) {
      int slot = (i<<8) + tid, r = slot >> 3, g = (slot & 7) ^ (r & 7);
      gll16(&As[buf][((i<<8) + (wv<<6))*8], Ab + (size_t)r*C_ + k0 + (g<<3));
    }
#pragma unroll
    for (int i = 0; i < 2; ++i) {
      int slot = (i<<8) + tid, r = slot >> 3, g = (slot & 7) ^ (r & 7);
      gll16(&Bs[buf][((i<<8) + (wv<<6))*8], Bb + (size_t)r*C_ + k0 + (g<<3));
    }
  };

  floatx4 acc[2][4] = {};
  stage(0, 0);
  stage(1, 64);
  asm volatile("s_waitcnt vmcnt(6)" ::: "memory");
  __builtin_amdgcn_s_barrier();
  __builtin_amdgcn_sched_barrier(0);

  int cur = 0;
  for (int it = 0; it < 16; ++it) {
    bhalf8 af[2][2], bfr[2][4];
#pragma unroll
    for (int ks = 0; ks < 2; ++ks) {
#pragma unroll
      for (int rt = 0; rt < 2; ++rt) {
        int row = (wv<<5) + rt*16 + l15;
        af[ks][rt] = *(const bhalf8*)&As[cur][(row<<6) + ((((ks<<2)+quad) ^ (row&7))<<3)];
      }
#pragma unroll
      for (int ct = 0; ct < 4; ++ct) {
        int row = ct*16 + l15;
        bfr[ks][ct] = *(const bhalf8*)&Bs[cur][(row<<6) + ((((ks<<2)+quad) ^ (row&7))<<3)];
      }
    }
    const bool pf = (it < 14);
    if (pf) {
      int nb = cur + 2; if (nb >= 3) nb -= 3;
      stage(nb, (it + 2) << 6);
    }
    __builtin_amdgcn_s_barrier();
    asm volatile("s_waitcnt lgkmcnt(0)" ::: "memory");
    __builtin_amdgcn_sched_barrier(0);
    __builtin_amdgcn_s_setprio(1);
#pragma unroll
    for (int ks = 0; ks < 2; ++ks)
#pragma unroll
      for (int rt = 0; rt < 2; ++rt)
#pragma unroll
        for (int ct = 0; ct < 4; ++ct)
          acc[rt][ct] = __builtin_amdgcn_mfma_f32_16x16x32_bf16(af[ks][rt], bfr[ks][ct], acc[rt][ct], 0, 0, 0);
    __builtin_amdgcn_s_setprio(0);
    if (pf) { asm volatile("s_waitcnt vmcnt(6)" ::: "memory"); }
    else    { asm volatile("s_waitcnt vmcnt(0)" ::: "memory"); }
    __builtin_amdgcn_s_barrier();
    __builtin_amdgcn_sched_barrier(0);
    if (++cur == 3) cur = 0;
  }

#pragma unroll
  for (int rt = 0; rt < 2; ++rt)
#pragma unroll
    for (int r = 0; r < 4; ++r) {
      int n = m0 + (wv<<5) + rt*16 + quad*4 + r;
#pragma unroll
      for (int ct = 0; ct < 4; ++ct)
        Cf[(size_t)n * C_ + n0 + ct*16 + l15] = acc[rt][ct][r];
    }
}

// Per-segment state summaries + per-64-chunk summaries Pc (j<3).
__global__ __launch_bounds__(256) void seg_state(
    const short* __restrict__ Kt, const short* __restrict__ Vt,
    short* __restrict__ Pseg, short* __restrict__ Pc)
{
  __shared__ __align__(16) short Ks[2][64*64];
  __shared__ __align__(16) short Vs[2][64*64];
  const int tid = threadIdx.x, lane = tid & 63, wv = tid >> 6;
  const int l15 = lane & 15, quad = lane >> 4;
  const int wrow = wv << 4;
  const int bh = blockIdx.x >> 3, p = blockIdx.x & 7;
  const int h = bh & 15;
  const float log2g = log2f(1.f - exp2f(-5.f - (float)h));
  const float g64 = exp2f(log2g * 64.f);

  float wgt[16];
#pragma unroll
  for (int ks = 0; ks < 2; ++ks)
#pragma unroll
    for (int i = 0; i < 8; ++i)
      wgt[ks*8 + i] = exp2f(log2g * (float)(64 - (ks*32 + (quad<<3) + i)));

  const short* Ktg = Kt + (size_t)bh*DH_*T_;
  const short* Vtg = Vt + (size_t)bh*DH_*T_;

  auto stage = [&](int buf, int jc) {
    const int m0 = ((p<<2) + jc) << 6;
#pragma unroll
    for (int i = 0; i < 2; ++i) {
      int slot = (i<<8) + tid;
      int r = slot >> 3, g = (slot & 7) ^ (r & 7);
      gll16(&Ks[buf][((i<<8) + (wv<<6))*8], Ktg + (size_t)r*T_ + m0 + (g<<3));
      gll16(&Vs[buf][((i<<8) + (wv<<6))*8], Vtg + (size_t)r*T_ + m0 + (g<<3));
    }
  };

  floatx4 acc[4] = {};
  stage(0, 0);
  int cur = 0;
  for (int j = 0; j < 4; ++j) {
    __syncthreads();
    if (j < 3) stage(cur ^ 1, j + 1);
    floatx4 pc[4] = {};
#pragma unroll
    for (int ks = 0; ks < 2; ++ks) {
      int row = wrow + l15;
      bhalf8 va = *(const bhalf8*)&Vs[cur][(row<<6) + ((((ks<<2)+quad) ^ (row&7))<<3)];
      bhalf8 aw;
#pragma unroll
      for (int i = 0; i < 8; ++i) aw[i] = f2bf(bf2f(va[i]) * wgt[ks*8 + i]);
      bhalf8 bk[4];
#pragma unroll
      for (int ct = 0; ct < 4; ++ct) {
        int kr = ct*16 + l15;
        bk[ct] = *(const bhalf8*)&Ks[cur][(kr<<6) + ((((ks<<2)+quad) ^ (kr&7))<<3)];
      }
#pragma unroll
      for (int ct = 0; ct < 4; ++ct)
        pc[ct] = __builtin_amdgcn_mfma_f32_16x16x32_bf16(aw, bk[ct], pc[ct], 0, 0, 0);
    }
#pragma unroll
    for (int ct = 0; ct < 4; ++ct)
#pragma unroll
      for (int r = 0; r < 4; ++r) acc[ct][r] = acc[ct][r]*g64 + pc[ct][r];
    if (j < 3) {
      size_t cbase = (size_t)((bh<<5) + (p<<2) + j) * 2 * 4096;
#pragma unroll
      for (int ct = 0; ct < 4; ++ct)
#pragma unroll
        for (int r = 0; r < 4; ++r) {
          int e = wrow + (quad<<2) + r, d = ct*16 + l15;
          float x = pc[ct][r];
          short hi = f2bf(x);
          short lo = f2bf(x - bf2f(hi));
          Pc[cbase + e*64 + d]        = hi;
          Pc[cbase + 4096 + e*64 + d] = lo;
        }
    }
    cur ^= 1;
  }
  size_t base = (size_t)(bh*8 + p) * 2 * 4096;
#pragma unroll
  for (int ct = 0; ct < 4; ++ct)
#pragma unroll
    for (int r = 0; r < 4; ++r) {
      int e = wrow + (quad<<2) + r, d = ct*16 + l15;
      float x = acc[ct][r];
      short hi = f2bf(x);
      short lo = f2bf(x - bf2f(hi));
      Pseg[base + e*64 + d]        = hi;
      Pseg[base + 4096 + e*64 + d] = lo;
    }
}

// Chunked retention: grid 1024 uniform blocks = (bh, chunk).
__global__ __launch_bounds__(256) void retention_chunk(
    const short* __restrict__ Qb, const short* __restrict__ Kb,
    const short* __restrict__ Vt,
    const short* __restrict__ Pc, const short* __restrict__ Pseg,
    const float* __restrict__ gnw, const float* __restrict__ gnb,
    short* __restrict__ Xn)
{
  __shared__ __align__(16) short Vs[64*64];
  __shared__ __align__(16) short KSs[64*64];
  __shared__ __align__(16) short Sh[64*64];
  __shared__ __align__(16) short Sl[64*64];

  const int tid = threadIdx.x, lane = tid & 63, wv = tid >> 6;
  const int l15 = lane & 15, quad = lane >> 4;
  const int wrow = wv << 4;

  const int idx = blockIdx.x;
  const int bh = idx & 31;
  const int cc = idx >> 5;
  const int c  = ((cc & 7) << 2) | (cc >> 3);
  const int p = c >> 2, j = c & 3;
  const int b = bh >> 4, h = bh & 15;
  const int n0 = c << 6;

  const float log2g = log2f(1.f - exp2f(-5.f - (float)h));

  const short* Kg  = Kb + (size_t)bh*T_*DH_;
  const short* Vtg = Vt + (size_t)bh*DH_*T_;

#pragma unroll
  for (int i = 0; i < 2; ++i) {
    int slot = (i<<8) + tid;
    int r = slot >> 3, g = (slot & 7) ^ (r & 7);
    gll16(&KSs[((i<<8) + (wv<<6))*8], Kg  + (size_t)(n0 + r)*DH_ + (g<<3));
    gll16(&Vs[((i<<8) + (wv<<6))*8],  Vtg + (size_t)r*T_ + n0 + (g<<3));
  }

  const short* Qg = Qb + ((size_t)bh*T_ + n0 + wrow) * DH_;
  bhalf8 aq[2];
#pragma unroll
  for (int ks = 0; ks < 2; ++ks)
    aq[ks] = *(const bhalf8*)(Qg + (size_t)l15*DH_ + ks*32 + quad*8);

  float rowf[4], colf0[4];
#pragma unroll
  for (int r = 0; r < 4; ++r)
    rowf[r] = exp2f(log2g * (float)(wrow + (quad<<2) + r)) * 0.125f;
#pragma unroll
  for (int ct = 0; ct < 4; ++ct)
    colf0[ct] = exp2f(-log2g * (float)(ct*16 + l15));

  const bool has_state = (c > 0);

  floatx4 st[4] = {};
  for (int jp = 0; jp < j; ++jp) {
    float wexp = log2g * (float)((j - 1 - jp) << 6);
    if (wexp < -34.f) continue;
    float w = exp2f(wexp);
    const short* Pg = Pc + (size_t)((bh<<5) + (p<<2) + jp) * 2 * 4096;
#pragma unroll
    for (int ct = 0; ct < 4; ++ct)
#pragma unroll
      for (int r = 0; r < 4; ++r) {
        int e = wrow + (quad<<2) + r, d = ct*16 + l15;
        st[ct][r] += w * (bf2f(Pg[e*64 + d]) + bf2f(Pg[4096 + e*64 + d]));
      }
  }
  for (int pp = 0; pp < p; ++pp) {
    float wexp = log2g * (float)(n0 - ((pp + 1) << 8));
    if (wexp < -34.f) continue;
    float w = exp2f(wexp);
    const short* Pg = Pseg + (size_t)(bh*8 + pp) * 2 * 4096;
#pragma unroll
    for (int ct = 0; ct < 4; ++ct)
#pragma unroll
      for (int r = 0; r < 4; ++r) {
        int e = wrow + (quad<<2) + r, d = ct*16 + l15;
        st[ct][r] += w * (bf2f(Pg[e*64 + d]) + bf2f(Pg[4096 + e*64 + d]));
      }
  }
  if (has_state) {
#pragma unroll
    for (int ct = 0; ct < 4; ++ct)
#pragma unroll
      for (int r = 0; r < 4; ++r) {
        int e = wrow + (quad<<2) + r, d = ct*16 + l15;
        float x = st[ct][r];
        short hi = f2bf(x);
        short lo = f2bf(x - bf2f(hi));
        int addr = (e<<6) + ((((d>>3) ^ (e&7))<<3)) + (d&7);
        Sh[addr] = hi; Sl[addr] = lo;
      }
  }

  __syncthreads();

  floatx4 sacc[4] = {};
#pragma unroll
  for (int ks = 0; ks < 2; ++ks) {
    bhalf8 bk[4];
#pragma unroll
    for (int ct = 0; ct < 4; ++ct) {
      int row = ct*16 + l15;
      bk[ct] = *(const bhalf8*)&KSs[(row<<6) + ((((ks<<2)+quad) ^ (row&7))<<3)];
    }
#pragma unroll
    for (int ct = 0; ct < 4; ++ct)
      sacc[ct] = __builtin_amdgcn_mfma_f32_16x16x32_bf16(aq[ks], bk[ct], sacc[ct], 0, 0, 0);
  }
  __syncthreads();
#pragma unroll
  for (int ct = 0; ct < 4; ++ct) {
    float cf = colf0[ct];
    int colg = (ct<<1) + (l15>>3);
    int m = ct*16 + l15;
#pragma unroll
    for (int r = 0; r < 4; ++r) {
      int row = wrow + (quad<<2) + r;
      float v = (row >= m) ? sacc[ct][r] * (rowf[r] * cf) : 0.f;
      KSs[(row<<6) + ((colg ^ ((row>>1)&7))<<3) + (l15&7)] = f2bf(v);
    }
  }
  floatx4 oacc[4] = {};
#pragma unroll
  for (int ks = 0; ks < 2; ++ks) {
    int row = wrow + l15;
    bhalf8 as_ = *(const bhalf8*)&KSs[(row<<6) + ((((ks<<2)+quad) ^ ((row>>1)&7))<<3)];
    bhalf8 bv[4];
#pragma unroll
    for (int ct = 0; ct < 4; ++ct) {
      int vrow = ct*16 + l15;
      bv[ct] = *(const bhalf8*)&Vs[(vrow<<6) + ((((ks<<2)+quad) ^ (vrow&7))<<3)];
    }
#pragma unroll
    for (int ct = 0; ct < 4; ++ct)
      oacc[ct] = __builtin_amdgcn_mfma_f32_16x16x32_bf16(as_, bv[ct], oacc[ct], 0, 0, 0);
  }

  if (has_state) {
    floatx4 iacc[4] = {};
#pragma unroll
    for (int ks = 0; ks < 2; ++ks) {
      bhalf8 bhf[4], blf[4];
#pragma unroll
      for (int ct = 0; ct < 4; ++ct) {
        int er = ct*16 + l15;
        int ga = ((((ks<<2)+quad) ^ (er&7))<<3);
        bhf[ct] = *(const bhalf8*)&Sh[(er<<6) + ga];
        blf[ct] = *(const bhalf8*)&Sl[(er<<6) + ga];
      }
#pragma unroll
      for (int ct = 0; ct < 4; ++ct) {
        iacc[ct] = __builtin_amdgcn_mfma_f32_16x16x32_bf16(aq[ks], bhf[ct], iacc[ct], 0, 0, 0);
        iacc[ct] = __builtin_amdgcn_mfma_f32_16x16x32_bf16(aq[ks], blf[ct], iacc[ct], 0, 0, 0);
      }
    }
#pragma unroll
    for (int ct = 0; ct < 4; ++ct)
#pragma unroll
      for (int r = 0; r < 4; ++r)
        oacc[ct][r] += rowf[r] * iacc[ct][r];
  }

#pragma unroll
  for (int r = 0; r < 4; ++r) {
    float s1 = oacc[0][r] + oacc[1][r] + oacc[2][r] + oacc[3][r];
    float s2 = oacc[0][r]*oacc[0][r] + oacc[1][r]*oacc[1][r]
             + oacc[2][r]*oacc[2][r] + oacc[3][r]*oacc[3][r];
#pragma unroll
    for (int off = 1; off < 16; off <<= 1) {
      s1 += __shfl_xor(s1, off);
      s2 += __shfl_xor(s2, off);
    }
    float mean = s1 * (1.f/64.f);
    float var  = s2 * (1.f/64.f) - mean*mean;
    float rstd = rsqrtf(var + 1e-5f);
    int t = n0 + wrow + (quad<<2) + r;
    size_t obase = ((size_t)b*T_ + t)*C_ + h*DH_;
#pragma unroll
    for (int ct = 0; ct < 4; ++ct) {
      int d = ct*16 + l15;
      float y = (oacc[ct][r] - mean)*rstd*gnw[h*DH_ + d] + gnb[h*DH_ + d];
      Xn[obase + d] = f2bf(y);
    }
  }
}

extern "C" void kernel_launch(void* const* d_in, const int* in_sizes, int n_in,
                              void* d_out, int out_size, void* d_ws, size_t ws_size,
                              hipStream_t stream) {
  (void)in_sizes; (void)n_in; (void)out_size; (void)ws_size;
  const float* x   = (const float*)d_in[0];
  const float* Wq  = (const float*)d_in[1];
  const float* Wk  = (const float*)d_in[2];
  const float* Wv  = (const float*)d_in[3];
  const float* Wo  = (const float*)d_in[4];
  const float* gnw = (const float*)d_in[5];
  const float* gnb = (const float*)d_in[6];
  float* out = (float*)d_out;

  char* ws = (char*)d_ws;                 // 80 MB used
  short* Xb   = (short*)(ws);             // [0,8): x bf16
  short* Wqb  = (short*)(ws + (8u<<20));  // [8,14): Wq|Wk|Wv CONTIGUOUS (concat)
  short* Pseg = (short*)(ws + (8u<<20));  //   reused after qkv: segment states
  short* Wkb  = (short*)(ws + (10u<<20));
  short* Wvb  = (short*)(ws + (12u<<20));
  short* Wob  = (short*)(ws + (14u<<20));
  short* Qb   = (short*)(ws + (16u<<20)); // (B,H,T,DH)
  short* Kb   = (short*)(ws + (24u<<20)); // (B,H,T,DH)
  short* Vtw  = (short*)(ws + (32u<<20)); // V^T (B,H,DH,T)
  short* Xn   = (short*)(ws + (40u<<20)); // retention out (B,T,C) bf16
  short* Ktb  = (short*)(ws + (48u<<20)); // K^T (B,H,DH,T)
  short* Pcb  = (short*)(ws + (64u<<20)); // per-64-chunk summaries, 16 MB

  cvt_all<<<(M_*C_/4 + 4*(C_*C_/4)) / 256, 256, 0, stream>>>(
      x, Wq, Wk, Wv, Wo, Xb, Wqb, Wkb, Wvb, Wob);

  gemm_qkv<<<dim3(256), 512, 0, stream>>>(Xb, Wqb, Qb, Kb, Vtw, Ktb);
  seg_state<<<256, 256, 0, stream>>>(Ktb, Vtw, Pseg, Pcb);
  retention_chunk<<<1024, 256, 0, stream>>>(Qb, Kb, Vtw, Pcb, Pseg, gnw, gnb, Xn);
  gemm_out<<<dim3(16, 32), 256, 0, stream>>>(Xn, Wob, out);
}

// Round 5
// 164.413 us; speedup vs baseline: 1.2300x; 1.2300x over previous
//
#include <hip/hip_runtime.h>
#include <stdint.h>

#define B_ 2
#define T_ 2048
#define C_ 1024
#define H_ 16
#define DH_ 64
#define M_ (B_*T_)   // 4096

typedef short bhalf8 __attribute__((ext_vector_type(8)));
typedef float floatx4 __attribute__((ext_vector_type(4)));

__device__ __forceinline__ short f2bf(float f) {
  unsigned u = __float_as_uint(f);
  u += 0x7fffu + ((u >> 16) & 1u);   // round-to-nearest-even
  return (short)(u >> 16);
}
__device__ __forceinline__ float bf2f(short s) {
  return __uint_as_float(((unsigned)(unsigned short)s) << 16);
}

// async global->LDS, 16B per lane; lds_dst wave-uniform (lane -> +lane*16)
__device__ __forceinline__ void gll16(void* lds_dst, const void* g_src) {
  __builtin_amdgcn_global_load_lds(
      reinterpret_cast<const uint32_t __attribute__((address_space(1)))*>(
          reinterpret_cast<uintptr_t>(g_src)),
      reinterpret_cast<uint32_t __attribute__((address_space(3)))*>(
          reinterpret_cast<uintptr_t>(lds_dst)),
      16, 0, 0);
}

__global__ void cvt_all(
    const float* __restrict__ x,  const float* __restrict__ wq,
    const float* __restrict__ wk, const float* __restrict__ wv,
    const float* __restrict__ wo,
    short* __restrict__ xb, short* __restrict__ wqb, short* __restrict__ wkb,
    short* __restrict__ wvb, short* __restrict__ wob)
{
  int i = blockIdx.x * blockDim.x + threadIdx.x;
  const float* s; short* d; int off;
  if (i < (M_*C_/4)) { s = x; d = xb; off = i; }
  else {
    int j = i - M_*C_/4;
    int w = j >> 18;                     // C_*C_/4 == 1<<18
    off = j & ((1<<18) - 1);
    s = (w==0) ? wq : (w==1) ? wk : (w==2) ? wv : wo;
    d = (w==0) ? wqb : (w==1) ? wkb : (w==2) ? wvb : wob;
  }
  float4 v = ((const float4*)s)[off];
  short4 o;
  o.x = f2bf(v.x); o.y = f2bf(v.y); o.z = f2bf(v.z); o.w = f2bf(v.w);
  ((short4*)d)[off] = o;
}

// R14 = R11 gemm_qkv (reverted from R13's BN=192: its LDS epilogue pass-B
// column reads were a 32-way bank conflict, 12.3M conflict-cycles, 84 us).
// 256x256 tile, BK=64, 8 waves (2Mx4N), 128 KiB LDS, 4-phase counted-vmcnt
// pipeline. Grid 192 = 12 N-tiles (x<4 Q, x<8 K, x>=8 V; V swaps operands so
// C/D layout gives coalesced V^T store) x 16 M-tiles, XCD-swizzled. K-blocks
// also emit K^T via LDS-transpose epilogue (row-major b128 reads, conflict-ok).
__global__ __launch_bounds__(512, 2) void gemm_qkv(
    const short* __restrict__ X,
    const short* __restrict__ Wq, const short* __restrict__ Wk, const short* __restrict__ Wv,
    short* __restrict__ Qb, short* __restrict__ Kb, short* __restrict__ Vt,
    short* __restrict__ Kt)
{
  __shared__ __align__(16) short SM[4*256*64];            // 128 KiB
  short (*As)[256*64] = (short (*)[256*64])(SM);
  short (*Bs)[256*64] = (short (*)[256*64])(SM + 2*256*64);
  short* Ct = SM;                                          // 256x256 epilogue tile

  const int tid  = threadIdx.x;
  const int lane = tid & 63;
  const int wid  = tid >> 6;
  const int l15  = lane & 15;
  const int quad = lane >> 4;
  const int wr   = wid >> 2;          // 0..1  (M half)
  const int wc   = wid & 3;           // 0..3  (N quarter)
  const int K    = C_;

  const int bid = blockIdx.x;
  const int wg  = (bid & 7) * 24 + (bid >> 3);
  const int nx  = wg % 12;
  const int m0  = (wg / 12) << 8;

  int kind, nloc;                    // 0=Q 1=K 2=V
  const short *Ab, *Bb;
  if (nx < 4)      { kind = 0; nloc = nx << 8;       Ab = X  + (size_t)m0*K;   Bb = Wq + (size_t)nloc*K; }
  else if (nx < 8) { kind = 1; nloc = (nx - 4) << 8; Ab = X  + (size_t)m0*K;   Bb = Wk + (size_t)nloc*K; }
  else             { kind = 2; nloc = (nx - 8) << 8; Ab = Wv + (size_t)nloc*K; Bb = X  + (size_t)m0*K;   }

  const int r_loc = tid >> 3;        // 0..63: row within a 64-row quarter
  const int g_lin = tid & 7;

  auto stageU = [&](short* lds, const short* g, int q, int k0) {
    int row = (q << 6) + r_loc;
    int gs  = g_lin ^ (row & 7);     // pre-swizzled global source (m173)
    gll16(lds + (q << 12) + (wid << 9), g + (size_t)row * K + k0 + (gs << 3));
  };

  floatx4 acc[8][4] = {};

  // ---- prologue: stage tile 0; order = read priority of tile0.p1/p2 ----
  stageU(&Bs[0][0], Bb, 0, 0); stageU(&Bs[0][0], Bb, 1, 0);
  stageU(&Bs[0][0], Bb, 2, 0); stageU(&Bs[0][0], Bb, 3, 0);
  stageU(&As[0][0], Ab, 0, 0); stageU(&As[0][0], Ab, 2, 0);
  stageU(&As[0][0], Ab, 1, 0); stageU(&As[0][0], Ab, 3, 0);
  asm volatile("s_waitcnt vmcnt(2)" ::: "memory");   // allow A q1,q3 in flight
  __builtin_amdgcn_s_barrier();
  __builtin_amdgcn_sched_barrier(0);

  for (int t = 0; t < 16; ++t) {
    const int buf = t & 1, nbuf = buf ^ 1;
    const int kn = (t + 1) << 6;
    const bool pf = (t < 15);
    bhalf8 aF[4], bF[4];

    // -------- phase 1: ks=0, m-frags 0..3 (+ B ks=0) --------
#pragma unroll
    for (int i = 0; i < 4; ++i) {
      int row = (wr << 7) + (i << 4) + l15;
      aF[i] = *(const bhalf8*)&As[buf][(row << 6) + ((quad ^ (row & 7)) << 3)];
    }
#pragma unroll
    for (int n = 0; n < 4; ++n) {
      int row = (wc << 6) + (n << 4) + l15;
      bF[n] = *(const bhalf8*)&Bs[buf][(row << 6) + ((quad ^ (row & 7)) << 3)];
    }
    if (pf) { stageU(&Bs[nbuf][0], Bb, 0, kn); stageU(&Bs[nbuf][0], Bb, 1, kn); }
    __builtin_amdgcn_s_barrier();
    asm volatile("s_waitcnt lgkmcnt(0)" ::: "memory");
    __builtin_amdgcn_sched_barrier(0);
    __builtin_amdgcn_s_setprio(1);
#pragma unroll
    for (int i = 0; i < 4; ++i)
#pragma unroll
      for (int n = 0; n < 4; ++n)
        acc[i][n] = __builtin_amdgcn_mfma_f32_16x16x32_bf16(aF[i], bF[n], acc[i][n], 0, 0, 0);
    __builtin_amdgcn_s_setprio(0);
    if (pf) { asm volatile("s_waitcnt vmcnt(2)" ::: "memory"); }
    else    { asm volatile("s_waitcnt vmcnt(0)" ::: "memory"); }
    __builtin_amdgcn_s_barrier();
    __builtin_amdgcn_sched_barrier(0);

    // -------- phase 2: ks=0, m-frags 4..7 (reuse bF) --------
#pragma unroll
    for (int i = 0; i < 4; ++i) {
      int row = (wr << 7) + ((4 + i) << 4) + l15;
      aF[i] = *(const bhalf8*)&As[buf][(row << 6) + ((quad ^ (row & 7)) << 3)];
    }
    if (pf) { stageU(&Bs[nbuf][0], Bb, 2, kn); stageU(&Bs[nbuf][0], Bb, 3, kn); }
    __builtin_amdgcn_s_barrier();
    asm volatile("s_waitcnt lgkmcnt(0)" ::: "memory");
    __builtin_amdgcn_sched_barrier(0);
    __builtin_amdgcn_s_setprio(1);
#pragma unroll
    for (int i = 0; i < 4; ++i)
#pragma unroll
      for (int n = 0; n < 4; ++n)
        acc[4 + i][n] = __builtin_amdgcn_mfma_f32_16x16x32_bf16(aF[i], bF[n], acc[4 + i][n], 0, 0, 0);
    __builtin_amdgcn_s_setprio(0);
    asm volatile("s_waitcnt vmcnt(4)" ::: "memory");
    __builtin_amdgcn_s_barrier();
    __builtin_amdgcn_sched_barrier(0);

    // -------- phase 3: ks=1, m-frags 0..3 (+ B ks=1) --------
#pragma unroll
    for (int i = 0; i < 4; ++i) {
      int row = (wr << 7) + (i << 4) + l15;
      aF[i] = *(const bhalf8*)&As[buf][(row << 6) + (((4 + quad) ^ (row & 7)) << 3)];
    }
#pragma unroll
    for (int n = 0; n < 4; ++n) {
      int row = (wc << 6) + (n << 4) + l15;
      bF[n] = *(const bhalf8*)&Bs[buf][(row << 6) + (((4 + quad) ^ (row & 7)) << 3)];
    }
    if (pf) { stageU(&As[nbuf][0], Ab, 0, kn); stageU(&As[nbuf][0], Ab, 2, kn); }
    __builtin_amdgcn_s_barrier();
    asm volatile("s_waitcnt lgkmcnt(0)" ::: "memory");
    __builtin_amdgcn_sched_barrier(0);
    __builtin_amdgcn_s_setprio(1);
#pragma unroll
    for (int i = 0; i < 4; ++i)
#pragma unroll
      for (int n = 0; n < 4; ++n)
        acc[i][n] = __builtin_amdgcn_mfma_f32_16x16x32_bf16(aF[i], bF[n], acc[i][n], 0, 0, 0);
    __builtin_amdgcn_s_setprio(0);
    asm volatile("s_waitcnt vmcnt(6)" ::: "memory");
    __builtin_amdgcn_s_barrier();
    __builtin_amdgcn_sched_barrier(0);

    // -------- phase 4: ks=1, m-frags 4..7 (reuse bF) --------
#pragma unroll
    for (int i = 0; i < 4; ++i) {
      int row = (wr << 7) + ((4 + i) << 4) + l15;
      aF[i] = *(const bhalf8*)&As[buf][(row << 6) + (((4 + quad) ^ (row & 7)) << 3)];
    }
    if (pf) { stageU(&As[nbuf][0], Ab, 1, kn); stageU(&As[nbuf][0], Ab, 3, kn); }
    __builtin_amdgcn_s_barrier();
    asm volatile("s_waitcnt lgkmcnt(0)" ::: "memory");
    __builtin_amdgcn_sched_barrier(0);
    __builtin_amdgcn_s_setprio(1);
#pragma unroll
    for (int i = 0; i < 4; ++i)
#pragma unroll
      for (int n = 0; n < 4; ++n)
        acc[4 + i][n] = __builtin_amdgcn_mfma_f32_16x16x32_bf16(aF[i], bF[n], acc[4 + i][n], 0, 0, 0);
    __builtin_amdgcn_s_setprio(0);
    asm volatile("s_waitcnt vmcnt(2)" ::: "memory");
    __builtin_amdgcn_s_barrier();
    __builtin_amdgcn_sched_barrier(0);
  }
  // after the final phase-4 barrier every wave is done with As/Bs -> Ct reusable

  if (kind < 2) {                        // Q or K: RoPE epilogue -> (B,H,T,DH)
    short* Cb = kind ? Kb : Qb;
    const int hh = (nloc + (wc << 6)) >> 6;     // wave's 64-col chunk = 1 head
    const float frq0 = exp2f((float)l15        * (-0.4152410118609203f));
    const float frq1 = exp2f((float)(l15 + 16) * (-0.4152410118609203f));
    const int swz = (l15 & 7) << 3;             // Ct granule swizzle key
#pragma unroll
    for (int m = 0; m < 8; ++m)
#pragma unroll
      for (int r = 0; r < 4; ++r) {
        int tl = (wr << 7) + (m << 4) + (quad << 2) + r;   // token within 256-tile
        int n  = m0 + tl;
        int bb = n >> 11, tt = n & (T_ - 1);
        size_t base = ((size_t)(bb * H_ + hh) * T_ + tt) * DH_;
        float tf = (float)tt;
        float v0, v1, v2, v3;
        {
          float ang = tf * frq0;
          float sn = __sinf(ang), cs = __cosf(ang);
          float xlo = acc[m][0][r], xhi = acc[m][2][r];
          v0 = xlo * cs - xhi * sn;
          v1 = xhi * cs + xlo * sn;
          Cb[base + l15]      = f2bf(v0);
          Cb[base + l15 + 32] = f2bf(v1);
        }
        {
          float ang = tf * frq1;
          float sn = __sinf(ang), cs = __cosf(ang);
          float xlo = acc[m][1][r], xhi = acc[m][3][r];
          v2 = xlo * cs - xhi * sn;
          v3 = xhi * cs + xlo * sn;
          Cb[base + l15 + 16] = f2bf(v2);
          Cb[base + l15 + 48] = f2bf(v3);
        }
        if (kind == 1) {                 // also deposit into Ct for K^T emit
          int tswz = tl ^ swz;
          int cb = (wc << 6);
          Ct[(cb + l15)      * 256 + tswz] = f2bf(v0);
          Ct[(cb + l15 + 32) * 256 + tswz] = f2bf(v1);
          Ct[(cb + l15 + 16) * 256 + tswz] = f2bf(v2);
          Ct[(cb + l15 + 48) * 256 + tswz] = f2bf(v3);
        }
      }
    if (kind == 1) {                     // coalesced K^T store from Ct
      __syncthreads();
      const int hb = nloc >> 6;
#pragma unroll
      for (int rr = 0; rr < 16; ++rr) {
        int lin = rr * 512 + tid;        // 8192 16B-chunks = 256 c x 32 granules
        int cc_ = lin >> 5;              // column (head-local channel)
        int g   = lin & 31;              // t-granule (8 tokens)
        bhalf8 v = *(const bhalf8*)&Ct[cc_ * 256 + ((g ^ (cc_ & 7)) << 3)];
        int tg = m0 + (g << 3);
        int bb = tg >> 11, tt = tg & (T_ - 1);
        size_t dst = ((size_t)(bb * H_ + hb + (cc_ >> 6)) * DH_ + (cc_ & 63)) * T_ + tt;
        *(bhalf8*)&Kt[dst] = v;
      }
    }
  } else {                               // V: rows=channels, cols=tokens -> V^T
#pragma unroll
    for (int m = 0; m < 8; ++m)
#pragma unroll
      for (int r = 0; r < 4; ++r) {
        int o = nloc + (wr << 7) + (m << 4) + (quad << 2) + r;
#pragma unroll
        for (int n = 0; n < 4; ++n) {
          int tk = m0 + (wc << 6) + (n << 4) + l15;
          int bb = tk >> 11, tt = tk & (T_ - 1);
          Vt[(size_t)bb * (C_ * T_) + (size_t)o * T_ + tt] = f2bf(acc[m][n][r]);
        }
      }
  }
}

// Final projection. 3-buffer 2-tile-lookahead counted-vmcnt pipeline.
__global__ __launch_bounds__(256) void gemm_out(
    const short* __restrict__ A, const short* __restrict__ Bm, float* __restrict__ Cf)
{
  __shared__ __align__(16) short As[3][128*64];   // 16 KB per buf
  __shared__ __align__(16) short Bs[3][64*64];    // 8 KB per buf
  const int tid = threadIdx.x, lane = tid & 63, wv = tid >> 6;
  const int l15 = lane & 15, quad = lane >> 4;
  const int n0 = blockIdx.x << 6;
  const int m0 = blockIdx.y << 7;

  const short* Ab = A  + (size_t)m0 * C_;
  const short* Bb = Bm + (size_t)n0 * C_;

  auto stage = [&](int buf, int k0) {
#pragma unroll
    for (int i = 0; i < 4; ++i) {
      int slot = (i<<8) + tid, r = slot >> 3, g = (slot & 7) ^ (r & 7);
      gll16(&As[buf][((i<<8) + (wv<<6))*8], Ab + (size_t)r*C_ + k0 + (g<<3));
    }
#pragma unroll
    for (int i = 0; i < 2; ++i) {
      int slot = (i<<8) + tid, r = slot >> 3, g = (slot & 7) ^ (r & 7);
      gll16(&Bs[buf][((i<<8) + (wv<<6))*8], Bb + (size_t)r*C_ + k0 + (g<<3));
    }
  };

  floatx4 acc[2][4] = {};
  stage(0, 0);
  stage(1, 64);
  asm volatile("s_waitcnt vmcnt(6)" ::: "memory");
  __builtin_amdgcn_s_barrier();
  __builtin_amdgcn_sched_barrier(0);

  int cur = 0;
  for (int it = 0; it < 16; ++it) {
    bhalf8 af[2][2], bfr[2][4];
#pragma unroll
    for (int ks = 0; ks < 2; ++ks) {
#pragma unroll
      for (int rt = 0; rt < 2; ++rt) {
        int row = (wv<<5) + rt*16 + l15;
        af[ks][rt] = *(const bhalf8*)&As[cur][(row<<6) + ((((ks<<2)+quad) ^ (row&7))<<3)];
      }
#pragma unroll
      for (int ct = 0; ct < 4; ++ct) {
        int row = ct*16 + l15;
        bfr[ks][ct] = *(const bhalf8*)&Bs[cur][(row<<6) + ((((ks<<2)+quad) ^ (row&7))<<3)];
      }
    }
    const bool pf = (it < 14);
    if (pf) {
      int nb = cur + 2; if (nb >= 3) nb -= 3;
      stage(nb, (it + 2) << 6);
    }
    __builtin_amdgcn_s_barrier();
    asm volatile("s_waitcnt lgkmcnt(0)" ::: "memory");
    __builtin_amdgcn_sched_barrier(0);
    __builtin_amdgcn_s_setprio(1);
#pragma unroll
    for (int ks = 0; ks < 2; ++ks)
#pragma unroll
      for (int rt = 0; rt < 2; ++rt)
#pragma unroll
        for (int ct = 0; ct < 4; ++ct)
          acc[rt][ct] = __builtin_amdgcn_mfma_f32_16x16x32_bf16(af[ks][rt], bfr[ks][ct], acc[rt][ct], 0, 0, 0);
    __builtin_amdgcn_s_setprio(0);
    if (pf) { asm volatile("s_waitcnt vmcnt(6)" ::: "memory"); }
    else    { asm volatile("s_waitcnt vmcnt(0)" ::: "memory"); }
    __builtin_amdgcn_s_barrier();
    __builtin_amdgcn_sched_barrier(0);
    if (++cur == 3) cur = 0;
  }

#pragma unroll
  for (int rt = 0; rt < 2; ++rt)
#pragma unroll
    for (int r = 0; r < 4; ++r) {
      int n = m0 + (wv<<5) + rt*16 + quad*4 + r;
#pragma unroll
      for (int ct = 0; ct < 4; ++ct)
        Cf[(size_t)n * C_ + n0 + ct*16 + l15] = acc[rt][ct][r];
    }
}

// Per-segment state summaries. 256 blocks = bh*8 + p, single-barrier dbuf.
__global__ __launch_bounds__(256) void seg_state(
    const short* __restrict__ Kt, const short* __restrict__ Vt,
    short* __restrict__ Pseg)
{
  __shared__ __align__(16) short Ks[2][64*64];   // K^T [d][tok], swizzled
  __shared__ __align__(16) short Vs[2][64*64];   // V^T [e][tok], swizzled
  const int tid = threadIdx.x, lane = tid & 63, wv = tid >> 6;
  const int l15 = lane & 15, quad = lane >> 4;
  const int wrow = wv << 4;
  const int bh = blockIdx.x >> 3, p = blockIdx.x & 7;
  const int h = bh & 15;
  const float log2g = log2f(1.f - exp2f(-5.f - (float)h));
  const float g64 = exp2f(log2g * 64.f);

  float wgt[16];
#pragma unroll
  for (int ks = 0; ks < 2; ++ks)
#pragma unroll
    for (int i = 0; i < 8; ++i)
      wgt[ks*8 + i] = exp2f(log2g * (float)(64 - (ks*32 + (quad<<3) + i)));

  const short* Ktg = Kt + (size_t)bh*DH_*T_;
  const short* Vtg = Vt + (size_t)bh*DH_*T_;

  auto stage = [&](int buf, int jc) {
    const int m0 = ((p<<2) + jc) << 6;
#pragma unroll
    for (int i = 0; i < 2; ++i) {
      int slot = (i<<8) + tid;
      int r = slot >> 3, g = (slot & 7) ^ (r & 7);
      gll16(&Ks[buf][((i<<8) + (wv<<6))*8], Ktg + (size_t)r*T_ + m0 + (g<<3));
      gll16(&Vs[buf][((i<<8) + (wv<<6))*8], Vtg + (size_t)r*T_ + m0 + (g<<3));
    }
  };

  floatx4 acc[4] = {};
  stage(0, 0);
  int cur = 0;
  for (int j = 0; j < 4; ++j) {
    __syncthreads();
    if (j < 3) stage(cur ^ 1, j + 1);
#pragma unroll
    for (int ct = 0; ct < 4; ++ct)
#pragma unroll
      for (int r = 0; r < 4; ++r) acc[ct][r] *= g64;
#pragma unroll
    for (int ks = 0; ks < 2; ++ks) {
      int row = wrow + l15;
      bhalf8 va = *(const bhalf8*)&Vs[cur][(row<<6) + ((((ks<<2)+quad) ^ (row&7))<<3)];
      bhalf8 aw;
#pragma unroll
      for (int i = 0; i < 8; ++i) aw[i] = f2bf(bf2f(va[i]) * wgt[ks*8 + i]);
      bhalf8 bk[4];
#pragma unroll
      for (int ct = 0; ct < 4; ++ct) {
        int kr = ct*16 + l15;
        bk[ct] = *(const bhalf8*)&Ks[cur][(kr<<6) + ((((ks<<2)+quad) ^ (kr&7))<<3)];
      }
#pragma unroll
      for (int ct = 0; ct < 4; ++ct)
        acc[ct] = __builtin_amdgcn_mfma_f32_16x16x32_bf16(aw, bk[ct], acc[ct], 0, 0, 0);
    }
    cur ^= 1;
  }
  size_t base = (size_t)(bh*8 + p) * 2 * 4096;
#pragma unroll
  for (int ct = 0; ct < 4; ++ct)
#pragma unroll
    for (int r = 0; r < 4; ++r) {
      int e = wrow + (quad<<2) + r, d = ct*16 + l15;
      float x = acc[ct][r];
      short hi = f2bf(x);
      short lo = f2bf(x - bf2f(hi));
      Pseg[base + e*64 + d]        = hi;
      Pseg[base + 4096 + e*64 + d] = lo;
    }
}

// Chunked retention: grid 1024 uniform blocks = (bh, chunk).
__global__ __launch_bounds__(256) void retention_chunk(
    const short* __restrict__ Qb, const short* __restrict__ Kb,
    const short* __restrict__ Kt, const short* __restrict__ Vt,
    const short* __restrict__ Pseg,
    const float* __restrict__ gnw, const float* __restrict__ gnb,
    short* __restrict__ Xn)
{
  __shared__ __align__(16) short Vs[64*64];    // V^T [e][tok] (scan, then own)
  __shared__ __align__(16) short Kts[64*64];   // K^T [d][tok] (scan)
  __shared__ __align__(16) short KSs[64*64];   // K [tok][d], reused as Ss
  __shared__ __align__(16) short Sh[64*64];    // state hi [e][d]
  __shared__ __align__(16) short Sl[64*64];    // state lo [e][d]

  const int tid = threadIdx.x, lane = tid & 63, wv = tid >> 6;
  const int l15 = lane & 15, quad = lane >> 4;
  const int wrow = wv << 4;

  const int idx = blockIdx.x;
  const int bh = idx & 31;
  const int cc = idx >> 5;
  const int c  = ((cc & 7) << 2) | (cc >> 3);
  const int p = c >> 2, j = c & 3;
  const int b = bh >> 4, h = bh & 15;
  const int n0 = c << 6;

  const float log2g = log2f(1.f - exp2f(-5.f - (float)h));
  const float g64 = exp2f(log2g * 64.f);

  const short* Qg  = Qb + ((size_t)bh*T_ + n0 + wrow) * DH_;
  const short* Kg  = Kb + (size_t)bh*T_*DH_;
  const short* Ktg = Kt + (size_t)bh*DH_*T_;
  const short* Vtg = Vt + (size_t)bh*DH_*T_;

  bhalf8 aq[2];
#pragma unroll
  for (int ks = 0; ks < 2; ++ks)
    aq[ks] = *(const bhalf8*)(Qg + (size_t)l15*DH_ + ks*32 + quad*8);

  float rowf[4], colf0[4];
#pragma unroll
  for (int r = 0; r < 4; ++r)
    rowf[r] = exp2f(log2g * (float)(wrow + (quad<<2) + r)) * 0.125f;
#pragma unroll
  for (int ct = 0; ct < 4; ++ct)
    colf0[ct] = exp2f(-log2g * (float)(ct*16 + l15));

  const bool has_state = (c > 0);

  // ---- state scan over own-segment chunks 0..j-1 ----
  floatx4 st[4] = {};
  if (j > 0) {
    float wgt[16];
#pragma unroll
    for (int ks = 0; ks < 2; ++ks)
#pragma unroll
      for (int i = 0; i < 8; ++i)
        wgt[ks*8 + i] = exp2f(log2g * (float)(64 - (ks*32 + (quad<<3) + i)));
    for (int jp = 0; jp < j; ++jp) {
      if (log2g * (float)((j - 1 - jp) << 6) < -34.f) continue; // fully decayed
      const int m0 = ((p<<2) + jp) << 6;
      __syncthreads();
#pragma unroll
      for (int i = 0; i < 2; ++i) {
        int slot = (i<<8) + tid;
        int r = slot >> 3, g = (slot & 7) ^ (r & 7);
        gll16(&Kts[((i<<8) + (wv<<6))*8], Ktg + (size_t)r*T_ + m0 + (g<<3));
        gll16(&Vs[((i<<8) + (wv<<6))*8],  Vtg + (size_t)r*T_ + m0 + (g<<3));
      }
      __syncthreads();
#pragma unroll
      for (int ct = 0; ct < 4; ++ct)
#pragma unroll
        for (int r = 0; r < 4; ++r) st[ct][r] *= g64;
#pragma unroll
      for (int ks = 0; ks < 2; ++ks) {
        int row = wrow + l15;
        bhalf8 va = *(const bhalf8*)&Vs[(row<<6) + ((((ks<<2)+quad) ^ (row&7))<<3)];
        bhalf8 aw;
#pragma unroll
        for (int i = 0; i < 8; ++i) aw[i] = f2bf(bf2f(va[i]) * wgt[ks*8 + i]);
        bhalf8 bk[4];
#pragma unroll
        for (int ct = 0; ct < 4; ++ct) {
          int kr = ct*16 + l15;
          bk[ct] = *(const bhalf8*)&Kts[(kr<<6) + ((((ks<<2)+quad) ^ (kr&7))<<3)];
        }
#pragma unroll
        for (int ct = 0; ct < 4; ++ct)
          st[ct] = __builtin_amdgcn_mfma_f32_16x16x32_bf16(aw, bk[ct], st[ct], 0, 0, 0);
      }
    }
  }
  // ---- add weighted previous-segment summaries (256-token segments) ----
  for (int pp = 0; pp < p; ++pp) {
    float wexp = log2g * (float)(n0 - ((pp + 1) << 8));
    if (wexp < -34.f) continue;
    float w = exp2f(wexp);
    const short* Pg = Pseg + (size_t)(bh*8 + pp) * 2 * 4096;
#pragma unroll
    for (int ct = 0; ct < 4; ++ct)
#pragma unroll
      for (int r = 0; r < 4; ++r) {
        int e = wrow + (quad<<2) + r, d = ct*16 + l15;
        st[ct][r] += w * (bf2f(Pg[e*64 + d]) + bf2f(Pg[4096 + e*64 + d]));
      }
  }
  // ---- split state to bf16 hi/lo in LDS ----
  if (has_state) {
#pragma unroll
    for (int ct = 0; ct < 4; ++ct)
#pragma unroll
      for (int r = 0; r < 4; ++r) {
        int e = wrow + (quad<<2) + r, d = ct*16 + l15;
        float x = st[ct][r];
        short hi = f2bf(x);
        short lo = f2bf(x - bf2f(hi));
        int addr = (e<<6) + ((((d>>3) ^ (e&7))<<3)) + (d&7);
        Sh[addr] = hi; Sl[addr] = lo;
      }
  }

  // ---- stage own chunk: K token-major + V^T ----
  __syncthreads();                     // covers Sh/Sl writes + frees Vs/Kts
#pragma unroll
  for (int i = 0; i < 2; ++i) {
    int slot = (i<<8) + tid;
    int r = slot >> 3, g = (slot & 7) ^ (r & 7);
    gll16(&KSs[((i<<8) + (wv<<6))*8], Kg  + (size_t)(n0 + r)*DH_ + (g<<3));
    gll16(&Vs[((i<<8) + (wv<<6))*8],  Vtg + (size_t)r*T_ + n0 + (g<<3));
  }
  __syncthreads();

  // ---- intra: QK^T on diagonal chunk ----
  floatx4 sacc[4] = {};
#pragma unroll
  for (int ks = 0; ks < 2; ++ks) {
    bhalf8 bk[4];
#pragma unroll
    for (int ct = 0; ct < 4; ++ct) {
      int row = ct*16 + l15;
      bk[ct] = *(const bhalf8*)&KSs[(row<<6) + ((((ks<<2)+quad) ^ (row&7))<<3)];
    }
#pragma unroll
    for (int ct = 0; ct < 4; ++ct)
      sacc[ct] = __builtin_amdgcn_mfma_f32_16x16x32_bf16(aq[ks], bk[ct], sacc[ct], 0, 0, 0);
  }
  __syncthreads();                     // all waves done reading KSs -> reuse as Ss
#pragma unroll
  for (int ct = 0; ct < 4; ++ct) {
    float cf = colf0[ct];
    int colg = (ct<<1) + (l15>>3);
    int m = ct*16 + l15;
#pragma unroll
    for (int r = 0; r < 4; ++r) {
      int row = wrow + (quad<<2) + r;
      float v = (row >= m) ? sacc[ct][r] * (rowf[r] * cf) : 0.f;
      KSs[(row<<6) + ((colg ^ ((row>>1)&7))<<3) + (l15&7)] = f2bf(v);
    }
  }
  // no barrier: wave reads back only its own Ss rows
  floatx4 oacc[4] = {};
#pragma unroll
  for (int ks = 0; ks < 2; ++ks) {
    int row = wrow + l15;
    bhalf8 as_ = *(const bhalf8*)&KSs[(row<<6) + ((((ks<<2)+quad) ^ ((row>>1)&7))<<3)];
    bhalf8 bv[4];
#pragma unroll
    for (int ct = 0; ct < 4; ++ct) {
      int vrow = ct*16 + l15;
      bv[ct] = *(const bhalf8*)&Vs[(vrow<<6) + ((((ks<<2)+quad) ^ (vrow&7))<<3)];
    }
#pragma unroll
    for (int ct = 0; ct < 4; ++ct)
      oacc[ct] = __builtin_amdgcn_mfma_f32_16x16x32_bf16(as_, bv[ct], oacc[ct], 0, 0, 0);
  }

  // ---- inter: O += gamma^i/8 * Q @ St ----
  if (has_state) {
    floatx4 iacc[4] = {};
#pragma unroll
    for (int ks = 0; ks < 2; ++ks) {
      bhalf8 bhf[4], blf[4];
#pragma unroll
      for (int ct = 0; ct < 4; ++ct) {
        int er = ct*16 + l15;
        int ga = ((((ks<<2)+quad) ^ (er&7))<<3);
        bhf[ct] = *(const bhalf8*)&Sh[(er<<6) + ga];
        blf[ct] = *(const bhalf8*)&Sl[(er<<6) + ga];
      }
#pragma unroll
      for (int ct = 0; ct < 4; ++ct) {
        iacc[ct] = __builtin_amdgcn_mfma_f32_16x16x32_bf16(aq[ks], bhf[ct], iacc[ct], 0, 0, 0);
        iacc[ct] = __builtin_amdgcn_mfma_f32_16x16x32_bf16(aq[ks], blf[ct], iacc[ct], 0, 0, 0);
      }
    }
#pragma unroll
    for (int ct = 0; ct < 4; ++ct)
#pragma unroll
      for (int r = 0; r < 4; ++r)
        oacc[ct][r] += rowf[r] * iacc[ct][r];
  }

  // ---- fused GroupNorm over DH, write (B,T,C) bf16 ----
#pragma unroll
  for (int r = 0; r < 4; ++r) {
    float s1 = oacc[0][r] + oacc[1][r] + oacc[2][r] + oacc[3][r];
    float s2 = oacc[0][r]*oacc[0][r] + oacc[1][r]*oacc[1][r]
             + oacc[2][r]*oacc[2][r] + oacc[3][r]*oacc[3][r];
#pragma unroll
    for (int off = 1; off < 16; off <<= 1) {
      s1 += __shfl_xor(s1, off);
      s2 += __shfl_xor(s2, off);
    }
    float mean = s1 * (1.f/64.f);
    float var  = s2 * (1.f/64.f) - mean*mean;
    float rstd = rsqrtf(var + 1e-5f);
    int t = n0 + wrow + (quad<<2) + r;
    size_t obase = ((size_t)b*T_ + t)*C_ + h*DH_;
#pragma unroll
    for (int ct = 0; ct < 4; ++ct) {
      int d = ct*16 + l15;
      float y = (oacc[ct][r] - mean)*rstd*gnw[h*DH_ + d] + gnb[h*DH_ + d];
      Xn[obase + d] = f2bf(y);
    }
  }
}

extern "C" void kernel_launch(void* const* d_in, const int* in_sizes, int n_in,
                              void* d_out, int out_size, void* d_ws, size_t ws_size,
                              hipStream_t stream) {
  (void)in_sizes; (void)n_in; (void)out_size; (void)ws_size;
  const float* x   = (const float*)d_in[0];
  const float* Wq  = (const float*)d_in[1];
  const float* Wk  = (const float*)d_in[2];
  const float* Wv  = (const float*)d_in[3];
  const float* Wo  = (const float*)d_in[4];
  const float* gnw = (const float*)d_in[5];
  const float* gnb = (const float*)d_in[6];
  float* out = (float*)d_out;

  char* ws = (char*)d_ws;                 // 56 MB used
  short* Xb   = (short*)(ws);             // [0,8): x bf16
  short* Wqb  = (short*)(ws + (8u<<20));  // [8,12): Wq+Wk bf16; reused as Pseg (4 MB)
  short* Pseg = (short*)(ws + (8u<<20));  //   segment states, 32*8*2*4096 shorts
  short* Wkb  = (short*)(ws + (10u<<20));
  short* Wvb  = (short*)(ws + (12u<<20));
  short* Wob  = (short*)(ws + (14u<<20));
  short* Qb   = (short*)(ws + (16u<<20)); // (B,H,T,DH)
  short* Kb   = (short*)(ws + (24u<<20)); // (B,H,T,DH)
  short* Vtw  = (short*)(ws + (32u<<20)); // V^T (B,H,DH,T)
  short* Xn   = (short*)(ws + (40u<<20)); // retention out (B,T,C) bf16
  short* Ktb  = (short*)(ws + (48u<<20)); // K^T (B,H,DH,T) - written by gemm_qkv

  cvt_all<<<(M_*C_/4 + 4*(C_*C_/4)) / 256, 256, 0, stream>>>(
      x, Wq, Wk, Wv, Wo, Xb, Wqb, Wkb, Wvb, Wob);

  gemm_qkv<<<dim3(192), 512, 0, stream>>>(Xb, Wqb, Wkb, Wvb, Qb, Kb, Vtw, Ktb);
  seg_state<<<256, 256, 0, stream>>>(Ktb, Vtw, Pseg);
  retention_chunk<<<1024, 256, 0, stream>>>(Qb, Kb, Ktb, Vtw, Pseg, gnw, gnb, Xn);
  gemm_out<<<dim3(16, 32), 256, 0, stream>>>(Xn, Wob, out);
}

// Round 6
// 163.925 us; speedup vs baseline: 1.2337x; 1.0030x over previous
//
#include <hip/hip_runtime.h>
#include <stdint.h>

#define B_ 2
#define T_ 2048
#define C_ 1024
#define H_ 16
#define DH_ 64
#define M_ (B_*T_)   // 4096

typedef short bhalf8 __attribute__((ext_vector_type(8)));
typedef float floatx4 __attribute__((ext_vector_type(4)));

__device__ __forceinline__ short f2bf(float f) {
  unsigned u = __float_as_uint(f);
  u += 0x7fffu + ((u >> 16) & 1u);   // round-to-nearest-even
  return (short)(u >> 16);
}
__device__ __forceinline__ float bf2f(short s) {
  return __uint_as_float(((unsigned)(unsigned short)s) << 16);
}

// async global->LDS, 16B per lane; lds_dst wave-uniform (lane -> +lane*16)
__device__ __forceinline__ void gll16(void* lds_dst, const void* g_src) {
  __builtin_amdgcn_global_load_lds(
      reinterpret_cast<const uint32_t __attribute__((address_space(1)))*>(
          reinterpret_cast<uintptr_t>(g_src)),
      reinterpret_cast<uint32_t __attribute__((address_space(3)))*>(
          reinterpret_cast<uintptr_t>(lds_dst)),
      16, 0, 0);
}

__global__ void cvt_all(
    const float* __restrict__ x,  const float* __restrict__ wq,
    const float* __restrict__ wk, const float* __restrict__ wv,
    const float* __restrict__ wo,
    short* __restrict__ xb, short* __restrict__ wqb, short* __restrict__ wkb,
    short* __restrict__ wvb, short* __restrict__ wob)
{
  int i = blockIdx.x * blockDim.x + threadIdx.x;
  const float* s; short* d; int off;
  if (i < (M_*C_/4)) { s = x; d = xb; off = i; }
  else {
    int j = i - M_*C_/4;
    int w = j >> 18;                     // C_*C_/4 == 1<<18
    off = j & ((1<<18) - 1);
    s = (w==0) ? wq : (w==1) ? wk : (w==2) ? wv : wo;
    d = (w==0) ? wqb : (w==1) ? wkb : (w==2) ? wvb : wob;
  }
  float4 v = ((const float4*)s)[off];
  short4 o;
  o.x = f2bf(v.x); o.y = f2bf(v.y); o.z = f2bf(v.z); o.w = f2bf(v.w);
  ((short4*)d)[off] = o;
}

// R15: same 256x256/BK=64/8-wave/4-phase qkv as R14 but with re-ordered
// prefetch so EVERY load gets >=2 phases (~600cy) before its landing gate
// (was: A1,A3 issued p4, waited end-p1 = 1 phase).
// Issue plan per tile t (prefetch t+1): p1: B0,B1 ; p2: B2,B3 ;
// p3: A0,A2,A1,A3 ; p4: none.
// Gates: end-p1 vmcnt(2) [waits A1,A3(t), issued t-1.p3; pf? else 0]
//        end-p2 vmcnt(4) [slack only]
//        end-p3 none     [nothing must land]
//        end-p4 vmcnt(2) [waits B0..B3,A0,A2 of t+1; A1,A3 fly; pf? else 0]
__global__ __launch_bounds__(512, 2) void gemm_qkv(
    const short* __restrict__ X,
    const short* __restrict__ Wq, const short* __restrict__ Wk, const short* __restrict__ Wv,
    short* __restrict__ Qb, short* __restrict__ Kb, short* __restrict__ Vt,
    short* __restrict__ Kt)
{
  __shared__ __align__(16) short SM[4*256*64];            // 128 KiB
  short (*As)[256*64] = (short (*)[256*64])(SM);
  short (*Bs)[256*64] = (short (*)[256*64])(SM + 2*256*64);
  short* Ct = SM;                                          // 256x256 epilogue tile

  const int tid  = threadIdx.x;
  const int lane = tid & 63;
  const int wid  = tid >> 6;
  const int l15  = lane & 15;
  const int quad = lane >> 4;
  const int wr   = wid >> 2;          // 0..1  (M half)
  const int wc   = wid & 3;           // 0..3  (N quarter)
  const int K    = C_;

  const int bid = blockIdx.x;
  const int wg  = (bid & 7) * 24 + (bid >> 3);
  const int nx  = wg % 12;
  const int m0  = (wg / 12) << 8;

  int kind, nloc;                    // 0=Q 1=K 2=V
  const short *Ab, *Bb;
  if (nx < 4)      { kind = 0; nloc = nx << 8;       Ab = X  + (size_t)m0*K;   Bb = Wq + (size_t)nloc*K; }
  else if (nx < 8) { kind = 1; nloc = (nx - 4) << 8; Ab = X  + (size_t)m0*K;   Bb = Wk + (size_t)nloc*K; }
  else             { kind = 2; nloc = (nx - 8) << 8; Ab = Wv + (size_t)nloc*K; Bb = X  + (size_t)m0*K;   }

  const int r_loc = tid >> 3;        // 0..63: row within a 64-row quarter
  const int g_lin = tid & 7;

  auto stageU = [&](short* lds, const short* g, int q, int k0) {
    int row = (q << 6) + r_loc;
    int gs  = g_lin ^ (row & 7);     // pre-swizzled global source (m173)
    gll16(lds + (q << 12) + (wid << 9), g + (size_t)row * K + k0 + (gs << 3));
  };

  floatx4 acc[8][4] = {};

  // ---- prologue: stage tile 0; order = read priority of tile0.p1/p2 ----
  stageU(&Bs[0][0], Bb, 0, 0); stageU(&Bs[0][0], Bb, 1, 0);
  stageU(&Bs[0][0], Bb, 2, 0); stageU(&Bs[0][0], Bb, 3, 0);
  stageU(&As[0][0], Ab, 0, 0); stageU(&As[0][0], Ab, 2, 0);
  stageU(&As[0][0], Ab, 1, 0); stageU(&As[0][0], Ab, 3, 0);
  asm volatile("s_waitcnt vmcnt(2)" ::: "memory");   // allow A q1,q3 in flight
  __builtin_amdgcn_s_barrier();
  __builtin_amdgcn_sched_barrier(0);

  for (int t = 0; t < 16; ++t) {
    const int buf = t & 1, nbuf = buf ^ 1;
    const int kn = (t + 1) << 6;
    const bool pf = (t < 15);
    bhalf8 aF[4], bF[4];

    // -------- phase 1: ks=0, m-frags 0..3 (+ B ks=0); issue B0,B1 --------
#pragma unroll
    for (int i = 0; i < 4; ++i) {
      int row = (wr << 7) + (i << 4) + l15;
      aF[i] = *(const bhalf8*)&As[buf][(row << 6) + ((quad ^ (row & 7)) << 3)];
    }
#pragma unroll
    for (int n = 0; n < 4; ++n) {
      int row = (wc << 6) + (n << 4) + l15;
      bF[n] = *(const bhalf8*)&Bs[buf][(row << 6) + ((quad ^ (row & 7)) << 3)];
    }
    if (pf) { stageU(&Bs[nbuf][0], Bb, 0, kn); stageU(&Bs[nbuf][0], Bb, 1, kn); }
    __builtin_amdgcn_s_barrier();
    asm volatile("s_waitcnt lgkmcnt(0)" ::: "memory");
    __builtin_amdgcn_sched_barrier(0);
    __builtin_amdgcn_s_setprio(1);
#pragma unroll
    for (int i = 0; i < 4; ++i)
#pragma unroll
      for (int n = 0; n < 4; ++n)
        acc[i][n] = __builtin_amdgcn_mfma_f32_16x16x32_bf16(aF[i], bF[n], acc[i][n], 0, 0, 0);
    __builtin_amdgcn_s_setprio(0);
    if (pf) { asm volatile("s_waitcnt vmcnt(2)" ::: "memory"); }  // A1,A3(t) landed
    else    { asm volatile("s_waitcnt vmcnt(0)" ::: "memory"); }  // last tile drain
    __builtin_amdgcn_s_barrier();
    __builtin_amdgcn_sched_barrier(0);

    // -------- phase 2: ks=0, m-frags 4..7 (reuse bF); issue B2,B3 --------
#pragma unroll
    for (int i = 0; i < 4; ++i) {
      int row = (wr << 7) + ((4 + i) << 4) + l15;
      aF[i] = *(const bhalf8*)&As[buf][(row << 6) + ((quad ^ (row & 7)) << 3)];
    }
    if (pf) { stageU(&Bs[nbuf][0], Bb, 2, kn); stageU(&Bs[nbuf][0], Bb, 3, kn); }
    __builtin_amdgcn_s_barrier();
    asm volatile("s_waitcnt lgkmcnt(0)" ::: "memory");
    __builtin_amdgcn_sched_barrier(0);
    __builtin_amdgcn_s_setprio(1);
#pragma unroll
    for (int i = 0; i < 4; ++i)
#pragma unroll
      for (int n = 0; n < 4; ++n)
        acc[4 + i][n] = __builtin_amdgcn_mfma_f32_16x16x32_bf16(aF[i], bF[n], acc[4 + i][n], 0, 0, 0);
    __builtin_amdgcn_s_setprio(0);
    asm volatile("s_waitcnt vmcnt(4)" ::: "memory");   // slack only
    __builtin_amdgcn_s_barrier();
    __builtin_amdgcn_sched_barrier(0);

    // -------- phase 3: ks=1, m-frags 0..3 (+ B ks=1); issue A0,A2,A1,A3 ----
#pragma unroll
    for (int i = 0; i < 4; ++i) {
      int row = (wr << 7) + (i << 4) + l15;
      aF[i] = *(const bhalf8*)&As[buf][(row << 6) + (((4 + quad) ^ (row & 7)) << 3)];
    }
#pragma unroll
    for (int n = 0; n < 4; ++n) {
      int row = (wc << 6) + (n << 4) + l15;
      bF[n] = *(const bhalf8*)&Bs[buf][(row << 6) + (((4 + quad) ^ (row & 7)) << 3)];
    }
    if (pf) { stageU(&As[nbuf][0], Ab, 0, kn); stageU(&As[nbuf][0], Ab, 2, kn);
              stageU(&As[nbuf][0], Ab, 1, kn); stageU(&As[nbuf][0], Ab, 3, kn); }
    __builtin_amdgcn_s_barrier();
    asm volatile("s_waitcnt lgkmcnt(0)" ::: "memory");
    __builtin_amdgcn_sched_barrier(0);
    __builtin_amdgcn_s_setprio(1);
#pragma unroll
    for (int i = 0; i < 4; ++i)
#pragma unroll
      for (int n = 0; n < 4; ++n)
        acc[i][n] = __builtin_amdgcn_mfma_f32_16x16x32_bf16(aF[i], bF[n], acc[i][n], 0, 0, 0);
    __builtin_amdgcn_s_setprio(0);
    __builtin_amdgcn_s_barrier();                      // no landing requirement
    __builtin_amdgcn_sched_barrier(0);

    // -------- phase 4: ks=1, m-frags 4..7 (reuse bF); no issues --------
#pragma unroll
    for (int i = 0; i < 4; ++i) {
      int row = (wr << 7) + ((4 + i) << 4) + l15;
      aF[i] = *(const bhalf8*)&As[buf][(row << 6) + (((4 + quad) ^ (row & 7)) << 3)];
    }
    __builtin_amdgcn_s_barrier();
    asm volatile("s_waitcnt lgkmcnt(0)" ::: "memory");
    __builtin_amdgcn_sched_barrier(0);
    __builtin_amdgcn_s_setprio(1);
#pragma unroll
    for (int i = 0; i < 4; ++i)
#pragma unroll
      for (int n = 0; n < 4; ++n)
        acc[4 + i][n] = __builtin_amdgcn_mfma_f32_16x16x32_bf16(aF[i], bF[n], acc[4 + i][n], 0, 0, 0);
    __builtin_amdgcn_s_setprio(0);
    if (pf) { asm volatile("s_waitcnt vmcnt(2)" ::: "memory"); }  // B*,A0,A2 landed
    else    { asm volatile("s_waitcnt vmcnt(0)" ::: "memory"); }
    __builtin_amdgcn_s_barrier();
    __builtin_amdgcn_sched_barrier(0);
  }
  // after the final phase-4 barrier every wave is done with As/Bs -> Ct reusable

  if (kind < 2) {                        // Q or K: RoPE epilogue -> (B,H,T,DH)
    short* Cb = kind ? Kb : Qb;
    const int hh = (nloc + (wc << 6)) >> 6;     // wave's 64-col chunk = 1 head
    const float frq0 = exp2f((float)l15        * (-0.4152410118609203f));
    const float frq1 = exp2f((float)(l15 + 16) * (-0.4152410118609203f));
    const int swz = (l15 & 7) << 3;             // Ct granule swizzle key
#pragma unroll
    for (int m = 0; m < 8; ++m)
#pragma unroll
      for (int r = 0; r < 4; ++r) {
        int tl = (wr << 7) + (m << 4) + (quad << 2) + r;   // token within 256-tile
        int n  = m0 + tl;
        int bb = n >> 11, tt = n & (T_ - 1);
        size_t base = ((size_t)(bb * H_ + hh) * T_ + tt) * DH_;
        float tf = (float)tt;
        float v0, v1, v2, v3;
        {
          float ang = tf * frq0;
          float sn = __sinf(ang), cs = __cosf(ang);
          float xlo = acc[m][0][r], xhi = acc[m][2][r];
          v0 = xlo * cs - xhi * sn;
          v1 = xhi * cs + xlo * sn;
          Cb[base + l15]      = f2bf(v0);
          Cb[base + l15 + 32] = f2bf(v1);
        }
        {
          float ang = tf * frq1;
          float sn = __sinf(ang), cs = __cosf(ang);
          float xlo = acc[m][1][r], xhi = acc[m][3][r];
          v2 = xlo * cs - xhi * sn;
          v3 = xhi * cs + xlo * sn;
          Cb[base + l15 + 16] = f2bf(v2);
          Cb[base + l15 + 48] = f2bf(v3);
        }
        if (kind == 1) {                 // also deposit into Ct for K^T emit
          int tswz = tl ^ swz;
          int cb = (wc << 6);
          Ct[(cb + l15)      * 256 + tswz] = f2bf(v0);
          Ct[(cb + l15 + 32) * 256 + tswz] = f2bf(v1);
          Ct[(cb + l15 + 16) * 256 + tswz] = f2bf(v2);
          Ct[(cb + l15 + 48) * 256 + tswz] = f2bf(v3);
        }
      }
    if (kind == 1) {                     // coalesced K^T store from Ct
      __syncthreads();
      const int hb = nloc >> 6;
#pragma unroll
      for (int rr = 0; rr < 16; ++rr) {
        int lin = rr * 512 + tid;        // 8192 16B-chunks = 256 c x 32 granules
        int cc_ = lin >> 5;              // column (head-local channel)
        int g   = lin & 31;              // t-granule (8 tokens)
        bhalf8 v = *(const bhalf8*)&Ct[cc_ * 256 + ((g ^ (cc_ & 7)) << 3)];
        int tg = m0 + (g << 3);
        int bb = tg >> 11, tt = tg & (T_ - 1);
        size_t dst = ((size_t)(bb * H_ + hb + (cc_ >> 6)) * DH_ + (cc_ & 63)) * T_ + tt;
        *(bhalf8*)&Kt[dst] = v;
      }
    }
  } else {                               // V: rows=channels, cols=tokens -> V^T
#pragma unroll
    for (int m = 0; m < 8; ++m)
#pragma unroll
      for (int r = 0; r < 4; ++r) {
        int o = nloc + (wr << 7) + (m << 4) + (quad << 2) + r;
#pragma unroll
        for (int n = 0; n < 4; ++n) {
          int tk = m0 + (wc << 6) + (n << 4) + l15;
          int bb = tk >> 11, tt = tk & (T_ - 1);
          Vt[(size_t)bb * (C_ * T_) + (size_t)o * T_ + tt] = f2bf(acc[m][n][r]);
        }
      }
  }
}

// Final projection. 3-buffer 2-tile-lookahead counted-vmcnt pipeline.
__global__ __launch_bounds__(256) void gemm_out(
    const short* __restrict__ A, const short* __restrict__ Bm, float* __restrict__ Cf)
{
  __shared__ __align__(16) short As[3][128*64];   // 16 KB per buf
  __shared__ __align__(16) short Bs[3][64*64];    // 8 KB per buf
  const int tid = threadIdx.x, lane = tid & 63, wv = tid >> 6;
  const int l15 = lane & 15, quad = lane >> 4;
  const int n0 = blockIdx.x << 6;
  const int m0 = blockIdx.y << 7;

  const short* Ab = A  + (size_t)m0 * C_;
  const short* Bb = Bm + (size_t)n0 * C_;

  auto stage = [&](int buf, int k0) {
#pragma unroll
    for (int i = 0; i < 4; ++i) {
      int slot = (i<<8) + tid, r = slot >> 3, g = (slot & 7) ^ (r & 7);
      gll16(&As[buf][((i<<8) + (wv<<6))*8], Ab + (size_t)r*C_ + k0 + (g<<3));
    }
#pragma unroll
    for (int i = 0; i < 2; ++i) {
      int slot = (i<<8) + tid, r = slot >> 3, g = (slot & 7) ^ (r & 7);
      gll16(&Bs[buf][((i<<8) + (wv<<6))*8], Bb + (size_t)r*C_ + k0 + (g<<3));
    }
  };

  floatx4 acc[2][4] = {};
  stage(0, 0);
  stage(1, 64);
  asm volatile("s_waitcnt vmcnt(6)" ::: "memory");
  __builtin_amdgcn_s_barrier();
  __builtin_amdgcn_sched_barrier(0);

  int cur = 0;
  for (int it = 0; it < 16; ++it) {
    bhalf8 af[2][2], bfr[2][4];
#pragma unroll
    for (int ks = 0; ks < 2; ++ks) {
#pragma unroll
      for (int rt = 0; rt < 2; ++rt) {
        int row = (wv<<5) + rt*16 + l15;
        af[ks][rt] = *(const bhalf8*)&As[cur][(row<<6) + ((((ks<<2)+quad) ^ (row&7))<<3)];
      }
#pragma unroll
      for (int ct = 0; ct < 4; ++ct) {
        int row = ct*16 + l15;
        bfr[ks][ct] = *(const bhalf8*)&Bs[cur][(row<<6) + ((((ks<<2)+quad) ^ (row&7))<<3)];
      }
    }
    const bool pf = (it < 14);
    if (pf) {
      int nb = cur + 2; if (nb >= 3) nb -= 3;
      stage(nb, (it + 2) << 6);
    }
    __builtin_amdgcn_s_barrier();
    asm volatile("s_waitcnt lgkmcnt(0)" ::: "memory");
    __builtin_amdgcn_sched_barrier(0);
    __builtin_amdgcn_s_setprio(1);
#pragma unroll
    for (int ks = 0; ks < 2; ++ks)
#pragma unroll
      for (int rt = 0; rt < 2; ++rt)
#pragma unroll
        for (int ct = 0; ct < 4; ++ct)
          acc[rt][ct] = __builtin_amdgcn_mfma_f32_16x16x32_bf16(af[ks][rt], bfr[ks][ct], acc[rt][ct], 0, 0, 0);
    __builtin_amdgcn_s_setprio(0);
    if (pf) { asm volatile("s_waitcnt vmcnt(6)" ::: "memory"); }
    else    { asm volatile("s_waitcnt vmcnt(0)" ::: "memory"); }
    __builtin_amdgcn_s_barrier();
    __builtin_amdgcn_sched_barrier(0);
    if (++cur == 3) cur = 0;
  }

#pragma unroll
  for (int rt = 0; rt < 2; ++rt)
#pragma unroll
    for (int r = 0; r < 4; ++r) {
      int n = m0 + (wv<<5) + rt*16 + quad*4 + r;
#pragma unroll
      for (int ct = 0; ct < 4; ++ct)
        Cf[(size_t)n * C_ + n0 + ct*16 + l15] = acc[rt][ct][r];
    }
}

// Per-segment state summaries. 256 blocks = bh*8 + p, single-barrier dbuf.
__global__ __launch_bounds__(256) void seg_state(
    const short* __restrict__ Kt, const short* __restrict__ Vt,
    short* __restrict__ Pseg)
{
  __shared__ __align__(16) short Ks[2][64*64];   // K^T [d][tok], swizzled
  __shared__ __align__(16) short Vs[2][64*64];   // V^T [e][tok], swizzled
  const int tid = threadIdx.x, lane = tid & 63, wv = tid >> 6;
  const int l15 = lane & 15, quad = lane >> 4;
  const int wrow = wv << 4;
  const int bh = blockIdx.x >> 3, p = blockIdx.x & 7;
  const int h = bh & 15;
  const float log2g = log2f(1.f - exp2f(-5.f - (float)h));
  const float g64 = exp2f(log2g * 64.f);

  float wgt[16];
#pragma unroll
  for (int ks = 0; ks < 2; ++ks)
#pragma unroll
    for (int i = 0; i < 8; ++i)
      wgt[ks*8 + i] = exp2f(log2g * (float)(64 - (ks*32 + (quad<<3) + i)));

  const short* Ktg = Kt + (size_t)bh*DH_*T_;
  const short* Vtg = Vt + (size_t)bh*DH_*T_;

  auto stage = [&](int buf, int jc) {
    const int m0 = ((p<<2) + jc) << 6;
#pragma unroll
    for (int i = 0; i < 2; ++i) {
      int slot = (i<<8) + tid;
      int r = slot >> 3, g = (slot & 7) ^ (r & 7);
      gll16(&Ks[buf][((i<<8) + (wv<<6))*8], Ktg + (size_t)r*T_ + m0 + (g<<3));
      gll16(&Vs[buf][((i<<8) + (wv<<6))*8], Vtg + (size_t)r*T_ + m0 + (g<<3));
    }
  };

  floatx4 acc[4] = {};
  stage(0, 0);
  int cur = 0;
  for (int j = 0; j < 4; ++j) {
    __syncthreads();
    if (j < 3) stage(cur ^ 1, j + 1);
#pragma unroll
    for (int ct = 0; ct < 4; ++ct)
#pragma unroll
      for (int r = 0; r < 4; ++r) acc[ct][r] *= g64;
#pragma unroll
    for (int ks = 0; ks < 2; ++ks) {
      int row = wrow + l15;
      bhalf8 va = *(const bhalf8*)&Vs[cur][(row<<6) + ((((ks<<2)+quad) ^ (row&7))<<3)];
      bhalf8 aw;
#pragma unroll
      for (int i = 0; i < 8; ++i) aw[i] = f2bf(bf2f(va[i]) * wgt[ks*8 + i]);
      bhalf8 bk[4];
#pragma unroll
      for (int ct = 0; ct < 4; ++ct) {
        int kr = ct*16 + l15;
        bk[ct] = *(const bhalf8*)&Ks[cur][(kr<<6) + ((((ks<<2)+quad) ^ (kr&7))<<3)];
      }
#pragma unroll
      for (int ct = 0; ct < 4; ++ct)
        acc[ct] = __builtin_amdgcn_mfma_f32_16x16x32_bf16(aw, bk[ct], acc[ct], 0, 0, 0);
    }
    cur ^= 1;
  }
  size_t base = (size_t)(bh*8 + p) * 2 * 4096;
#pragma unroll
  for (int ct = 0; ct < 4; ++ct)
#pragma unroll
    for (int r = 0; r < 4; ++r) {
      int e = wrow + (quad<<2) + r, d = ct*16 + l15;
      float x = acc[ct][r];
      short hi = f2bf(x);
      short lo = f2bf(x - bf2f(hi));
      Pseg[base + e*64 + d]        = hi;
      Pseg[base + 4096 + e*64 + d] = lo;
    }
}

// Chunked retention: grid 1024 uniform blocks = (bh, chunk).
__global__ __launch_bounds__(256) void retention_chunk(
    const short* __restrict__ Qb, const short* __restrict__ Kb,
    const short* __restrict__ Kt, const short* __restrict__ Vt,
    const short* __restrict__ Pseg,
    const float* __restrict__ gnw, const float* __restrict__ gnb,
    short* __restrict__ Xn)
{
  __shared__ __align__(16) short Vs[64*64];    // V^T [e][tok] (scan, then own)
  __shared__ __align__(16) short Kts[64*64];   // K^T [d][tok] (scan)
  __shared__ __align__(16) short KSs[64*64];   // K [tok][d], reused as Ss
  __shared__ __align__(16) short Sh[64*64];    // state hi [e][d]
  __shared__ __align__(16) short Sl[64*64];    // state lo [e][d]

  const int tid = threadIdx.x, lane = tid & 63, wv = tid >> 6;
  const int l15 = lane & 15, quad = lane >> 4;
  const int wrow = wv << 4;

  const int idx = blockIdx.x;
  const int bh = idx & 31;
  const int cc = idx >> 5;
  const int c  = ((cc & 7) << 2) | (cc >> 3);
  const int p = c >> 2, j = c & 3;
  const int b = bh >> 4, h = bh & 15;
  const int n0 = c << 6;

  const float log2g = log2f(1.f - exp2f(-5.f - (float)h));
  const float g64 = exp2f(log2g * 64.f);

  const short* Qg  = Qb + ((size_t)bh*T_ + n0 + wrow) * DH_;
  const short* Kg  = Kb + (size_t)bh*T_*DH_;
  const short* Ktg = Kt + (size_t)bh*DH_*T_;
  const short* Vtg = Vt + (size_t)bh*DH_*T_;

  bhalf8 aq[2];
#pragma unroll
  for (int ks = 0; ks < 2; ++ks)
    aq[ks] = *(const bhalf8*)(Qg + (size_t)l15*DH_ + ks*32 + quad*8);

  float rowf[4], colf0[4];
#pragma unroll
  for (int r = 0; r < 4; ++r)
    rowf[r] = exp2f(log2g * (float)(wrow + (quad<<2) + r)) * 0.125f;
#pragma unroll
  for (int ct = 0; ct < 4; ++ct)
    colf0[ct] = exp2f(-log2g * (float)(ct*16 + l15));

  const bool has_state = (c > 0);

  // ---- state scan over own-segment chunks 0..j-1 ----
  floatx4 st[4] = {};
  if (j > 0) {
    float wgt[16];
#pragma unroll
    for (int ks = 0; ks < 2; ++ks)
#pragma unroll
      for (int i = 0; i < 8; ++i)
        wgt[ks*8 + i] = exp2f(log2g * (float)(64 - (ks*32 + (quad<<3) + i)));
    for (int jp = 0; jp < j; ++jp) {
      if (log2g * (float)((j - 1 - jp) << 6) < -34.f) continue; // fully decayed
      const int m0 = ((p<<2) + jp) << 6;
      __syncthreads();
#pragma unroll
      for (int i = 0; i < 2; ++i) {
        int slot = (i<<8) + tid;
        int r = slot >> 3, g = (slot & 7) ^ (r & 7);
        gll16(&Kts[((i<<8) + (wv<<6))*8], Ktg + (size_t)r*T_ + m0 + (g<<3));
        gll16(&Vs[((i<<8) + (wv<<6))*8],  Vtg + (size_t)r*T_ + m0 + (g<<3));
      }
      __syncthreads();
#pragma unroll
      for (int ct = 0; ct < 4; ++ct)
#pragma unroll
        for (int r = 0; r < 4; ++r) st[ct][r] *= g64;
#pragma unroll
      for (int ks = 0; ks < 2; ++ks) {
        int row = wrow + l15;
        bhalf8 va = *(const bhalf8*)&Vs[(row<<6) + ((((ks<<2)+quad) ^ (row&7))<<3)];
        bhalf8 aw;
#pragma unroll
        for (int i = 0; i < 8; ++i) aw[i] = f2bf(bf2f(va[i]) * wgt[ks*8 + i]);
        bhalf8 bk[4];
#pragma unroll
        for (int ct = 0; ct < 4; ++ct) {
          int kr = ct*16 + l15;
          bk[ct] = *(const bhalf8*)&Kts[(kr<<6) + ((((ks<<2)+quad) ^ (kr&7))<<3)];
        }
#pragma unroll
        for (int ct = 0; ct < 4; ++ct)
          st[ct] = __builtin_amdgcn_mfma_f32_16x16x32_bf16(aw, bk[ct], st[ct], 0, 0, 0);
      }
    }
  }
  // ---- add weighted previous-segment summaries (256-token segments) ----
  for (int pp = 0; pp < p; ++pp) {
    float wexp = log2g * (float)(n0 - ((pp + 1) << 8));
    if (wexp < -34.f) continue;
    float w = exp2f(wexp);
    const short* Pg = Pseg + (size_t)(bh*8 + pp) * 2 * 4096;
#pragma unroll
    for (int ct = 0; ct < 4; ++ct)
#pragma unroll
      for (int r = 0; r < 4; ++r) {
        int e = wrow + (quad<<2) + r, d = ct*16 + l15;
        st[ct][r] += w * (bf2f(Pg[e*64 + d]) + bf2f(Pg[4096 + e*64 + d]));
      }
  }
  // ---- split state to bf16 hi/lo in LDS ----
  if (has_state) {
#pragma unroll
    for (int ct = 0; ct < 4; ++ct)
#pragma unroll
      for (int r = 0; r < 4; ++r) {
        int e = wrow + (quad<<2) + r, d = ct*16 + l15;
        float x = st[ct][r];
        short hi = f2bf(x);
        short lo = f2bf(x - bf2f(hi));
        int addr = (e<<6) + ((((d>>3) ^ (e&7))<<3)) + (d&7);
        Sh[addr] = hi; Sl[addr] = lo;
      }
  }

  // ---- stage own chunk: K token-major + V^T ----
  __syncthreads();                     // covers Sh/Sl writes + frees Vs/Kts
#pragma unroll
  for (int i = 0; i < 2; ++i) {
    int slot = (i<<8) + tid;
    int r = slot >> 3, g = (slot & 7) ^ (r & 7);
    gll16(&KSs[((i<<8) + (wv<<6))*8], Kg  + (size_t)(n0 + r)*DH_ + (g<<3));
    gll16(&Vs[((i<<8) + (wv<<6))*8],  Vtg + (size_t)r*T_ + n0 + (g<<3));
  }
  __syncthreads();

  // ---- intra: QK^T on diagonal chunk ----
  floatx4 sacc[4] = {};
#pragma unroll
  for (int ks = 0; ks < 2; ++ks) {
    bhalf8 bk[4];
#pragma unroll
    for (int ct = 0; ct < 4; ++ct) {
      int row = ct*16 + l15;
      bk[ct] = *(const bhalf8*)&KSs[(row<<6) + ((((ks<<2)+quad) ^ (row&7))<<3)];
    }
#pragma unroll
    for (int ct = 0; ct < 4; ++ct)
      sacc[ct] = __builtin_amdgcn_mfma_f32_16x16x32_bf16(aq[ks], bk[ct], sacc[ct], 0, 0, 0);
  }
  __syncthreads();                     // all waves done reading KSs -> reuse as Ss
#pragma unroll
  for (int ct = 0; ct < 4; ++ct) {
    float cf = colf0[ct];
    int colg = (ct<<1) + (l15>>3);
    int m = ct*16 + l15;
#pragma unroll
    for (int r = 0; r < 4; ++r) {
      int row = wrow + (quad<<2) + r;
      float v = (row >= m) ? sacc[ct][r] * (rowf[r] * cf) : 0.f;
      KSs[(row<<6) + ((colg ^ ((row>>1)&7))<<3) + (l15&7)] = f2bf(v);
    }
  }
  // no barrier: wave reads back only its own Ss rows
  floatx4 oacc[4] = {};
#pragma unroll
  for (int ks = 0; ks < 2; ++ks) {
    int row = wrow + l15;
    bhalf8 as_ = *(const bhalf8*)&KSs[(row<<6) + ((((ks<<2)+quad) ^ ((row>>1)&7))<<3)];
    bhalf8 bv[4];
#pragma unroll
    for (int ct = 0; ct < 4; ++ct) {
      int vrow = ct*16 + l15;
      bv[ct] = *(const bhalf8*)&Vs[(vrow<<6) + ((((ks<<2)+quad) ^ (vrow&7))<<3)];
    }
#pragma unroll
    for (int ct = 0; ct < 4; ++ct)
      oacc[ct] = __builtin_amdgcn_mfma_f32_16x16x32_bf16(as_, bv[ct], oacc[ct], 0, 0, 0);
  }

  // ---- inter: O += gamma^i/8 * Q @ St ----
  if (has_state) {
    floatx4 iacc[4] = {};
#pragma unroll
    for (int ks = 0; ks < 2; ++ks) {
      bhalf8 bhf[4], blf[4];
#pragma unroll
      for (int ct = 0; ct < 4; ++ct) {
        int er = ct*16 + l15;
        int ga = ((((ks<<2)+quad) ^ (er&7))<<3);
        bhf[ct] = *(const bhalf8*)&Sh[(er<<6) + ga];
        blf[ct] = *(const bhalf8*)&Sl[(er<<6) + ga];
      }
#pragma unroll
      for (int ct = 0; ct < 4; ++ct) {
        iacc[ct] = __builtin_amdgcn_mfma_f32_16x16x32_bf16(aq[ks], bhf[ct], iacc[ct], 0, 0, 0);
        iacc[ct] = __builtin_amdgcn_mfma_f32_16x16x32_bf16(aq[ks], blf[ct], iacc[ct], 0, 0, 0);
      }
    }
#pragma unroll
    for (int ct = 0; ct < 4; ++ct)
#pragma unroll
      for (int r = 0; r < 4; ++r)
        oacc[ct][r] += rowf[r] * iacc[ct][r];
  }

  // ---- fused GroupNorm over DH, write (B,T,C) bf16 ----
#pragma unroll
  for (int r = 0; r < 4; ++r) {
    float s1 = oacc[0][r] + oacc[1][r] + oacc[2][r] + oacc[3][r];
    float s2 = oacc[0][r]*oacc[0][r] + oacc[1][r]*oacc[1][r]
             + oacc[2][r]*oacc[2][r] + oacc[3][r]*oacc[3][r];
#pragma unroll
    for (int off = 1; off < 16; off <<= 1) {
      s1 += __shfl_xor(s1, off);
      s2 += __shfl_xor(s2, off);
    }
    float mean = s1 * (1.f/64.f);
    float var  = s2 * (1.f/64.f) - mean*mean;
    float rstd = rsqrtf(var + 1e-5f);
    int t = n0 + wrow + (quad<<2) + r;
    size_t obase = ((size_t)b*T_ + t)*C_ + h*DH_;
#pragma unroll
    for (int ct = 0; ct < 4; ++ct) {
      int d = ct*16 + l15;
      float y = (oacc[ct][r] - mean)*rstd*gnw[h*DH_ + d] + gnb[h*DH_ + d];
      Xn[obase + d] = f2bf(y);
    }
  }
}

extern "C" void kernel_launch(void* const* d_in, const int* in_sizes, int n_in,
                              void* d_out, int out_size, void* d_ws, size_t ws_size,
                              hipStream_t stream) {
  (void)in_sizes; (void)n_in; (void)out_size; (void)ws_size;
  const float* x   = (const float*)d_in[0];
  const float* Wq  = (const float*)d_in[1];
  const float* Wk  = (const float*)d_in[2];
  const float* Wv  = (const float*)d_in[3];
  const float* Wo  = (const float*)d_in[4];
  const float* gnw = (const float*)d_in[5];
  const float* gnb = (const float*)d_in[6];
  float* out = (float*)d_out;

  char* ws = (char*)d_ws;                 // 56 MB used
  short* Xb   = (short*)(ws);             // [0,8): x bf16
  short* Wqb  = (short*)(ws + (8u<<20));  // [8,12): Wq+Wk bf16; reused as Pseg (4 MB)
  short* Pseg = (short*)(ws + (8u<<20));  //   segment states, 32*8*2*4096 shorts
  short* Wkb  = (short*)(ws + (10u<<20));
  short* Wvb  = (short*)(ws + (12u<<20));
  short* Wob  = (short*)(ws + (14u<<20));
  short* Qb   = (short*)(ws + (16u<<20)); // (B,H,T,DH)
  short* Kb   = (short*)(ws + (24u<<20)); // (B,H,T,DH)
  short* Vtw  = (short*)(ws + (32u<<20)); // V^T (B,H,DH,T)
  short* Xn   = (short*)(ws + (40u<<20)); // retention out (B,T,C) bf16
  short* Ktb  = (short*)(ws + (48u<<20)); // K^T (B,H,DH,T) - written by gemm_qkv

  cvt_all<<<(M_*C_/4 + 4*(C_*C_/4)) / 256, 256, 0, stream>>>(
      x, Wq, Wk, Wv, Wo, Xb, Wqb, Wkb, Wvb, Wob);

  gemm_qkv<<<dim3(192), 512, 0, stream>>>(Xb, Wqb, Wkb, Wvb, Qb, Kb, Vtw, Ktb);
  seg_state<<<256, 256, 0, stream>>>(Ktb, Vtw, Pseg);
  retention_chunk<<<1024, 256, 0, stream>>>(Qb, Kb, Ktb, Vtw, Pseg, gnw, gnb, Xn);
  gemm_out<<<dim3(16, 32), 256, 0, stream>>>(Xn, Wob, out);
}